// Round 10
// baseline (1217.776 us; speedup 1.0000x reference)
//
#include <hip/hip_runtime.h>
#include <math.h>

#define B_ 8192
#define K_ 32
#define D_ 768
#define H_ 256
#define T_ 16
#define S_ 2

typedef unsigned int uint;
typedef unsigned short ushort;
typedef __attribute__((ext_vector_type(8))) short bf16x8;
typedef __attribute__((ext_vector_type(4))) float f32x4;

// ---------- wave (64-lane) reductions ----------
__device__ __forceinline__ float wsum(float v) {
  v += __shfl_xor(v, 32); v += __shfl_xor(v, 16); v += __shfl_xor(v, 8);
  v += __shfl_xor(v, 4);  v += __shfl_xor(v, 2);  v += __shfl_xor(v, 1);
  return v;
}
__device__ __forceinline__ float wmaxr(float v) {
  v = fmaxf(v, __shfl_xor(v, 32)); v = fmaxf(v, __shfl_xor(v, 16));
  v = fmaxf(v, __shfl_xor(v, 8));  v = fmaxf(v, __shfl_xor(v, 4));
  v = fmaxf(v, __shfl_xor(v, 2));  v = fmaxf(v, __shfl_xor(v, 1));
  return v;
}

// split fp32 -> (hi bf16 trunc, lo bf16 trunc of exact remainder), packed 2/uint
__device__ __forceinline__ void split4(const float4 f, uint2& h, uint2& lo) {
  const uint ux = __float_as_uint(f.x), uy = __float_as_uint(f.y);
  const uint uz = __float_as_uint(f.z), uw = __float_as_uint(f.w);
  h.x = (uy & 0xFFFF0000u) | (ux >> 16);
  h.y = (uw & 0xFFFF0000u) | (uz >> 16);
  const float rx = f.x - __uint_as_float(ux & 0xFFFF0000u);
  const float ry = f.y - __uint_as_float(uy & 0xFFFF0000u);
  const float rz = f.z - __uint_as_float(uz & 0xFFFF0000u);
  const float rw = f.w - __uint_as_float(uw & 0xFFFF0000u);
  lo.x = (__float_as_uint(ry) & 0xFFFF0000u) | (__float_as_uint(rx) >> 16);
  lo.y = (__float_as_uint(rw) & 0xFFFF0000u) | (__float_as_uint(rz) >> 16);
}

__device__ __forceinline__ bf16x8 mk8(const uint2 a, const uint2 b) {
  union { uint4 u; bf16x8 v; } x;
  x.u = make_uint4(a.x, a.y, b.x, b.y);
  return x.v;
}
__device__ __forceinline__ bf16x8 u2b(const uint4 u) {
  union { uint4 u; bf16x8 v; } x;
  x.u = u;
  return x.v;
}

__device__ __forceinline__ float dot4(const float4 a, const float4 b) {
  float s = a.x * b.x;
  s = fmaf(a.y, b.y, s); s = fmaf(a.z, b.z, s); s = fmaf(a.w, b.w, s);
  return s;
}

// B frag tiling (NB = N/16): elem(n,k) -> ((ks*NB + nb)*64 + (nl | kc<<4))*8 + kb
// A frag direct-load: lane l, tile mi -> row mi*16+(l&15), k-chunk (l>>4)*8

// ---------- fold stage 1: WkinT fp32, Wv_in fp32, Wc_in -> hi/lo bf16 frag-tiled (NB=16) ----------
__global__ __launch_bounds__(256)
void fold_kernel(const float* __restrict__ Wk_a, const float* __restrict__ Wv_a,
                 const float* __restrict__ Wc,  const float* __restrict__ W_in,
                 float* __restrict__ WkinT, float* __restrict__ Wv_in,
                 ushort* __restrict__ Bh, ushort* __restrict__ Bl)
{
  const int i = blockIdx.x;
  const int m = blockIdx.y;
  const float* Wx = (m == 0) ? Wk_a : ((m == 1) ? Wv_a : Wc);
  const int t = threadIdx.x;
  float a0 = 0.f, a1 = 0.f, a2 = 0.f;
  for (int k = 0; k < H_; k++) {
    const float wv = Wx[i * H_ + k];
    const float* row = W_in + (size_t)k * D_;
    a0 = fmaf(wv, row[t], a0);
    a1 = fmaf(wv, row[t + 256], a1);
    a2 = fmaf(wv, row[t + 512], a2);
  }
  if (m == 0) {
    WkinT[(size_t)t * H_ + i] = a0;
    WkinT[(size_t)(t + 256) * H_ + i] = a1;
    WkinT[(size_t)(t + 512) * H_ + i] = a2;
  } else if (m == 1) {
    float* o = Wv_in + (size_t)i * D_;
    o[t] = a0; o[t + 256] = a1; o[t + 512] = a2;
  } else {
    const float vals[3] = {a0, a1, a2};
#pragma unroll
    for (int j = 0; j < 3; j++) {
      const int k = t + j * 256;
      const float v = vals[j];
      const int idx = (((k >> 5) * 16 + (i >> 4)) * 64 + ((i & 15) | (((k >> 3) & 3) << 4))) * 8 + (k & 7);
      const uint u = __float_as_uint(v);
      Bh[idx] = (ushort)(u >> 16);
      const float rr = v - __uint_as_float(u & 0xFFFF0000u);
      Bl[idx] = (ushort)(__float_as_uint(rr) >> 16);
    }
  }
}

// ---------- all weight tilings in one launch ----------
struct TileJob { const float* W; ushort* Bh; ushort* Bl; int NB; int K; int rows; };
struct TileJobs { TileJob j[6]; };

__global__ __launch_bounds__(256)
void tile_all(TileJobs jobs)
{
  const TileJob J = jobs.j[blockIdx.y];
  const int n = blockIdx.x;
  if (n >= J.rows) return;
  const int t = threadIdx.x;
  for (int k = t; k < J.K; k += 256) {
    const float v = J.W[(size_t)n * J.K + k];
    const int idx = (((k >> 5) * J.NB + (n >> 4)) * 64 + ((n & 15) | (((k >> 3) & 3) << 4))) * 8 + (k & 7);
    const uint u = __float_as_uint(v);
    J.Bh[idx] = (ushort)(u >> 16);
    const float rr = v - __uint_as_float(u & 0xFFFF0000u);
    J.Bl[idx] = (ushort)(__float_as_uint(rr) >> 16);
  }
}

// ---------- l2-normalize topic prototypes ----------
__global__ __launch_bounds__(256)
void proto_kernel(const float* __restrict__ tpro, float* __restrict__ pro)
{
  const int w = threadIdx.x >> 6, l = threadIdx.x & 63;
  for (int r = w; r < T_; r += 4) {
    const float4 v = *(const float4*)(tpro + (size_t)r * H_ + l * 4);
    const float n = fmaxf(sqrtf(wsum(v.x * v.x + v.y * v.y + v.z * v.z + v.w * v.w)), 1e-12f);
    float4 o; o.x = v.x / n; o.y = v.y / n; o.z = v.z / n; o.w = v.w / n;
    *(float4*)(pro + (size_t)r * H_ + l * 4) = o;
  }
}

// ---------- fold stage 2: attention/query-path weight folds ----------
__global__ __launch_bounds__(256)
void fold2_kernel(const float* __restrict__ Wq_a, const float* __restrict__ bq_a,
                  const float* __restrict__ bk_a, const float* __restrict__ Wo_a,
                  const float* __restrict__ bo_a, const float* __restrict__ bv_a,
                  const float* __restrict__ Wq,   const float* __restrict__ ln_w,
                  const float* __restrict__ ln_b, const float* __restrict__ WkinT,
                  const float* __restrict__ Wv_in,
                  float* __restrict__ Bqk, float* __restrict__ bqk,
                  float* __restrict__ Wvo, float* __restrict__ bvo,
                  float* __restrict__ Wqp, float* __restrict__ bqp,
                  float* __restrict__ vqbk, float* __restrict__ qcst)
{
  __shared__ float rd_s[4];
  const int n = blockIdx.x, t = threadIdx.x, w = t >> 6, l = t & 63;
  float s = 0.f;
  for (int hh = 0; hh < H_; hh++)
    s = fmaf(Wq_a[hh * H_ + t], WkinT[(size_t)n * H_ + hh], s);
  Bqk[(size_t)n * H_ + t] = s;
  float p = bq_a[t] * WkinT[(size_t)n * H_ + t];
  p = wsum(p);
  if (l == 0) rd_s[w] = p;
  __syncthreads();
  if (t == 0) bqk[n] = rd_s[0] + rd_s[1] + rd_s[2] + rd_s[3];
  if (n < H_) {
    float a0 = 0.f, a1 = 0.f, a2 = 0.f;
    for (int hh = 0; hh < H_; hh++) {
      const float wo = Wo_a[n * H_ + hh];
      const float* rowv = Wv_in + (size_t)hh * D_;
      a0 = fmaf(wo, rowv[t], a0);
      a1 = fmaf(wo, rowv[t + 256], a1);
      a2 = fmaf(wo, rowv[t + 512], a2);
    }
    Wvo[(size_t)n * D_ + t] = a0;
    Wvo[(size_t)n * D_ + t + 256] = a1;
    Wvo[(size_t)n * D_ + t + 512] = a2;
    float pb = Wo_a[n * H_ + t] * bv_a[t];
    pb = wsum(pb);
    __syncthreads();
    if (l == 0) rd_s[w] = pb;
    __syncthreads();
    if (t == 0) bvo[n] = rd_s[0] + rd_s[1] + rd_s[2] + rd_s[3] + bo_a[n];
    Wqp[n * H_ + t] = Wq[n * H_ + t] * ln_w[t];
    float pq = Wq[n * H_ + t] * ln_b[t];
    pq = wsum(pq);
    __syncthreads();
    if (l == 0) rd_s[w] = pq;
    __syncthreads();
    if (t == 0) bqp[n] = rd_s[0] + rd_s[1] + rd_s[2] + rd_s[3];
  }
  if (n == 0) {
    float sv = 0.f;
    for (int hh = 0; hh < H_; hh++) sv = fmaf(bk_a[hh], Wq_a[hh * H_ + t], sv);
    vqbk[t] = sv;
    float pc = bq_a[t] * bk_a[t];
    pc = wsum(pc);
    __syncthreads();
    if (l == 0) rd_s[w] = pc;
    __syncthreads();
    if (t == 0) qcst[0] = rd_s[0] + rd_s[1] + rd_s[2] + rd_s[3];
  }
}

// ---------- fused gemm_cn + cross-attention (v3: barrier-free K-loop, reg A-frags) ----------
// Block = 64 rows = batches {2b, 2b+1}. 4 waves, one per 64-col group; each wave
// direct-loads all 4 A row-tiles (L1/L2-served redundancy). No LDS in the K-loop.
__global__ __launch_bounds__(256, 3)
void gemm_cn_attn(const float* __restrict__ A, const ushort* __restrict__ Bh,
                  const ushort* __restrict__ Bl, const float* __restrict__ qkv,
                  const float* __restrict__ qr, const float* __restrict__ vqbk,
                  const float* __restrict__ qcst, float* __restrict__ C,
                  float* __restrict__ wce)
{
  __shared__ __align__(16) float4 qkv_s[384];   // 2 batches x 192
  __shared__ float sc_s[64], at_s[64], qbk_s[2];
  __shared__ float rsq[64][4];
  const int t = threadIdx.x, l = t & 63, w = t >> 6;

  for (int i = t; i < 384; i += 256)
    qkv_s[i] = ((const float4*)qkv)[(size_t)blockIdx.x * 384 + i];
  if (w < 2) {
    const float4 q4 = ((const float4*)qr)[((size_t)blockIdx.x * 2 + w) * 64 + l];
    const float4 v4 = ((const float4*)vqbk)[l];
    float p = wsum(dot4(q4, v4));
    if (l == 0) qbk_s[w] = p + qcst[0];
  }

  const float* Arow = A + ((size_t)blockIdx.x * 64 + (l & 15)) * 768 + (l >> 4) * 8;
  const ushort* Bhb = Bh + ((w * 4) * 64 + l) * 8;   // + ks*8192 + ni*512
  const ushort* Blb = Bl + ((w * 4) * 64 + l) * 8;
  const int qbase = (w >> 1) * 192 + (l >> 4) * 2;

  f32x4 acc[4][4];
#pragma unroll
  for (int i = 0; i < 4; i++)
#pragma unroll
    for (int j = 0; j < 4; j++) acc[i][j] = (f32x4)0.f;
  float sc = 0.f;
  __syncthreads();  // qkv_s ready; last barrier until after the K-loop

  for (int ks = 0; ks < 24; ks++) {
    uint4 bhv[4], blv[4];
#pragma unroll
    for (int ni = 0; ni < 4; ni++) {
      bhv[ni] = *(const uint4*)(Bhb + ks * 8192 + ni * 512);
      blv[ni] = *(const uint4*)(Blb + ks * 8192 + ni * 512);
    }
    const float4 q0 = qkv_s[qbase + ks * 8];
    const float4 q1 = qkv_s[qbase + ks * 8 + 1];
#pragma unroll
    for (int mi = 0; mi < 4; mi++) {
      const float4 f0 = *(const float4*)(Arow + (size_t)mi * 16 * 768 + ks * 32);
      const float4 f1 = *(const float4*)(Arow + (size_t)mi * 16 * 768 + ks * 32 + 4);
      if (mi == w) sc += dot4(f0, q0) + dot4(f1, q1);  // wave w scores rows w*16+(l&15)
      uint2 ha, la, hb, lb;
      split4(f0, ha, la); split4(f1, hb, lb);
      const bf16x8 ah = mk8(ha, hb);
      const bf16x8 al = mk8(la, lb);
#pragma unroll
      for (int ni = 0; ni < 4; ni++) {
        acc[mi][ni] = __builtin_amdgcn_mfma_f32_16x16x32_bf16(ah, u2b(bhv[ni]), acc[mi][ni], 0, 0, 0);
        acc[mi][ni] = __builtin_amdgcn_mfma_f32_16x16x32_bf16(al, u2b(bhv[ni]), acc[mi][ni], 0, 0, 0);
        acc[mi][ni] = __builtin_amdgcn_mfma_f32_16x16x32_bf16(ah, u2b(blv[ni]), acc[mi][ni], 0, 0, 0);
      }
    }
  }

  // ---- attention: reduce per-row scores over k-groups, softmax per batch, PV ----
  sc += __shfl_xor(sc, 16);
  sc += __shfl_xor(sc, 32);
  if (l < 16) sc_s[w * 16 + l] = sc;
  __syncthreads();
  if (w < 2) {  // wave w handles batch w (rows w*32..w*32+31)
    float s = (l < 32) ? (sc_s[w * 32 + l] + qbk_s[w]) * (1.f / 16.f) : -1e30f;
    const float m = wmaxr(s);
    const float e = (l < 32) ? expf(s - m) : 0.f;
    const float su = wsum(e);
    if (l < 32) at_s[w * 32 + l] = e / su;
  }
  __syncthreads();
  // PV: 384 float4 slots (2 batches x 192); ce re-read is L2/L3-served
#pragma unroll
  for (int p = 0; p < 2; p++) {
    const int slot = t + p * 256;
    if (slot < 384) {
      const int tb2 = slot >= 192;
      const int idx = slot - tb2 * 192;
      const float4* cb = (const float4*)A + ((size_t)blockIdx.x * 64 + tb2 * 32) * 192 + idx;
      float4 a = make_float4(0.f, 0.f, 0.f, 0.f);
#pragma unroll 4
      for (int c = 0; c < 32; c++) {
        const float av = at_s[tb2 * 32 + c];
        const float4 f = cb[c * 192];
        a.x = fmaf(av, f.x, a.x); a.y = fmaf(av, f.y, a.y);
        a.z = fmaf(av, f.z, a.z); a.w = fmaf(av, f.w, a.w);
      }
      ((float4*)wce)[((size_t)blockIdx.x * 2 + tb2) * 192 + idx] = a;
    }
  }

  // ---- fused epilogue: l2n + write cn ----
#pragma unroll
  for (int mi = 0; mi < 4; mi++)
#pragma unroll
    for (int rg = 0; rg < 4; rg++) {
      float p = 0.f;
#pragma unroll
      for (int ni = 0; ni < 4; ni++) { const float v = acc[mi][ni][rg]; p = fmaf(v, v, p); }
      p += __shfl_xor(p, 1); p += __shfl_xor(p, 2); p += __shfl_xor(p, 4); p += __shfl_xor(p, 8);
      if ((l & 15) == 0) rsq[mi * 16 + (l >> 4) * 4 + rg][w] = p;
    }
  __syncthreads();
  const size_t row0 = (size_t)blockIdx.x * 64;
#pragma unroll
  for (int mi = 0; mi < 4; mi++)
#pragma unroll
    for (int rg = 0; rg < 4; rg++) {
      const int rl = mi * 16 + (l >> 4) * 4 + rg;
      const float ssum = rsq[rl][0] + rsq[rl][1] + rsq[rl][2] + rsq[rl][3];
      const float inv = 1.f / fmaxf(sqrtf(ssum), 1e-12f);
#pragma unroll
      for (int ni = 0; ni < 4; ni++)
        C[(row0 + rl) * H_ + w * 64 + ni * 16 + (l & 15)] = acc[mi][ni][rg] * inv;
    }
}

// ---------- gemm ctx + residual + LayerNorm fused (v2: BM=32, barrier-free loop) ----------
__global__ __launch_bounds__(256)
void gemm_ctx_ln(const float* __restrict__ A, const ushort* __restrict__ Bh,
                 const ushort* __restrict__ Bl, const float* __restrict__ bvo,
                 const float* __restrict__ qr, float* __restrict__ xhat)
{
  __shared__ float red[32][4][2];
  const int t = threadIdx.x, l = t & 63, w = t >> 6;
  const float* Arow = A + ((size_t)blockIdx.x * 32 + (l & 15)) * 768 + (l >> 4) * 8;
  const ushort* Bhb = Bh + ((w * 4) * 64 + l) * 8;
  const ushort* Blb = Bl + ((w * 4) * 64 + l) * 8;

  f32x4 acc[2][4];
#pragma unroll
  for (int i = 0; i < 2; i++)
#pragma unroll
    for (int j = 0; j < 4; j++) acc[i][j] = (f32x4)0.f;

  for (int ks = 0; ks < 24; ks++) {
    uint4 bhv[4], blv[4];
#pragma unroll
    for (int ni = 0; ni < 4; ni++) {
      bhv[ni] = *(const uint4*)(Bhb + ks * 8192 + ni * 512);
      blv[ni] = *(const uint4*)(Blb + ks * 8192 + ni * 512);
    }
#pragma unroll
    for (int mi = 0; mi < 2; mi++) {
      const float4 f0 = *(const float4*)(Arow + (size_t)mi * 16 * 768 + ks * 32);
      const float4 f1 = *(const float4*)(Arow + (size_t)mi * 16 * 768 + ks * 32 + 4);
      uint2 ha, la, hb, lb;
      split4(f0, ha, la); split4(f1, hb, lb);
      const bf16x8 ah = mk8(ha, hb);
      const bf16x8 al = mk8(la, lb);
#pragma unroll
      for (int ni = 0; ni < 4; ni++) {
        acc[mi][ni] = __builtin_amdgcn_mfma_f32_16x16x32_bf16(ah, u2b(bhv[ni]), acc[mi][ni], 0, 0, 0);
        acc[mi][ni] = __builtin_amdgcn_mfma_f32_16x16x32_bf16(al, u2b(bhv[ni]), acc[mi][ni], 0, 0, 0);
        acc[mi][ni] = __builtin_amdgcn_mfma_f32_16x16x32_bf16(ah, u2b(blv[ni]), acc[mi][ni], 0, 0, 0);
      }
    }
  }

  // epilogue: x = acc + bvo + qr ; LN over rows ; write xhat
  const size_t row0 = (size_t)blockIdx.x * 32;
#pragma unroll
  for (int mi = 0; mi < 2; mi++)
#pragma unroll
    for (int rg = 0; rg < 4; rg++) {
      const int rl = mi * 16 + (l >> 4) * 4 + rg;
      float sx = 0.f, sxx = 0.f;
#pragma unroll
      for (int ni = 0; ni < 4; ni++) {
        const int col = w * 64 + ni * 16 + (l & 15);
        const float x = acc[mi][ni][rg] + bvo[col] + qr[(row0 + rl) * H_ + col];
        acc[mi][ni][rg] = x;
        sx += x; sxx = fmaf(x, x, sxx);
      }
      sx += __shfl_xor(sx, 1); sx += __shfl_xor(sx, 2); sx += __shfl_xor(sx, 4); sx += __shfl_xor(sx, 8);
      sxx += __shfl_xor(sxx, 1); sxx += __shfl_xor(sxx, 2); sxx += __shfl_xor(sxx, 4); sxx += __shfl_xor(sxx, 8);
      if ((l & 15) == 0) { red[rl][w][0] = sx; red[rl][w][1] = sxx; }
    }
  __syncthreads();
#pragma unroll
  for (int mi = 0; mi < 2; mi++)
#pragma unroll
    for (int rg = 0; rg < 4; rg++) {
      const int rl = mi * 16 + (l >> 4) * 4 + rg;
      const float SX = red[rl][0][0] + red[rl][1][0] + red[rl][2][0] + red[rl][3][0];
      const float SXX = red[rl][0][1] + red[rl][1][1] + red[rl][2][1] + red[rl][3][1];
      const float mu = SX * (1.f / H_);
      const float var = SXX * (1.f / H_) - mu * mu;
      const float isd = 1.f / sqrtf(var + 1e-5f);
#pragma unroll
      for (int ni = 0; ni < 4; ni++)
        xhat[(row0 + rl) * H_ + w * 64 + ni * 16 + (l & 15)] = (acc[mi][ni][rg] - mu) * isd;
    }
}

// ---------- generic split-bf16 MFMA GEMM (v2: barrier-free, reg A-frags, no LDS) ----------
template<int NKS, int NB, bool BIAS>
__global__ __launch_bounds__(256)
void gemm_bf(const float* __restrict__ A, const ushort* __restrict__ Bh,
             const ushort* __restrict__ Bl, const float* __restrict__ bias,
             float* __restrict__ C)
{
  const int t = threadIdx.x, l = t & 63, w = t >> 6;
  const int wr = w >> 1, wc = w & 1;
  const int Kd = NKS * 32, N = NB * 16;
  const float* Arow = A + ((size_t)blockIdx.x * 128 + wr * 64 + (l & 15)) * Kd + (l >> 4) * 8;
  const int nb0 = blockIdx.y * 4 + wc * 2;
  const ushort* Bhb = Bh + (nb0 * 64 + l) * 8;
  const ushort* Blb = Bl + (nb0 * 64 + l) * 8;

  f32x4 acc[4][2];
#pragma unroll
  for (int i = 0; i < 4; i++)
#pragma unroll
    for (int j = 0; j < 2; j++) acc[i][j] = (f32x4)0.f;

  for (int ks = 0; ks < NKS; ks++) {
    uint4 bhv[2], blv[2];
#pragma unroll
    for (int ni = 0; ni < 2; ni++) {
      bhv[ni] = *(const uint4*)(Bhb + ks * (NB * 512) + ni * 512);
      blv[ni] = *(const uint4*)(Blb + ks * (NB * 512) + ni * 512);
    }
#pragma unroll
    for (int mi = 0; mi < 4; mi++) {
      const float4 f0 = *(const float4*)(Arow + (size_t)mi * 16 * Kd + ks * 32);
      const float4 f1 = *(const float4*)(Arow + (size_t)mi * 16 * Kd + ks * 32 + 4);
      uint2 ha, la, hb, lb;
      split4(f0, ha, la); split4(f1, hb, lb);
      const bf16x8 ah = mk8(ha, hb);
      const bf16x8 al = mk8(la, lb);
#pragma unroll
      for (int ni = 0; ni < 2; ni++) {
        acc[mi][ni] = __builtin_amdgcn_mfma_f32_16x16x32_bf16(ah, u2b(bhv[ni]), acc[mi][ni], 0, 0, 0);
        acc[mi][ni] = __builtin_amdgcn_mfma_f32_16x16x32_bf16(al, u2b(bhv[ni]), acc[mi][ni], 0, 0, 0);
        acc[mi][ni] = __builtin_amdgcn_mfma_f32_16x16x32_bf16(ah, u2b(blv[ni]), acc[mi][ni], 0, 0, 0);
      }
    }
  }

  const size_t row0 = (size_t)blockIdx.x * 128 + wr * 64;
  const int col0 = blockIdx.y * 64 + wc * 32;
#pragma unroll
  for (int mi = 0; mi < 4; mi++)
#pragma unroll
    for (int ni = 0; ni < 2; ni++) {
      const int col = col0 + ni * 16 + (l & 15);
      const float bb = BIAS ? bias[col] : 0.f;
#pragma unroll
      for (int rg = 0; rg < 4; rg++) {
        const size_t row = row0 + mi * 16 + (l >> 4) * 4 + rg;
        C[row * N + col] = acc[mi][ni][rg] + bb;
      }
    }
}

// ---------- h = l2n(hraw); need = softmax(h@Wqt^T + bqt) ----------
__global__ __launch_bounds__(256)
void h_post(const float* __restrict__ hraw, const float* __restrict__ Wqt,
            const float* __restrict__ bqt, float* __restrict__ h, float* __restrict__ need)
{
  __shared__ float wq_s[T_ * H_];
  for (int i = threadIdx.x; i < T_ * H_; i += 256) wq_s[i] = Wqt[i];
  const int w = threadIdx.x >> 6, l = threadIdx.x & 63;
  const size_t r = (size_t)blockIdx.x * 4 + w;
  const float4 v = *(const float4*)(hraw + r * H_ + l * 4);
  const float n = fmaxf(sqrtf(wsum(v.x * v.x + v.y * v.y + v.z * v.z + v.w * v.w)), 1e-12f);
  float4 hn; hn.x = v.x / n; hn.y = v.y / n; hn.z = v.z / n; hn.w = v.w / n;
  *(float4*)(h + r * H_ + l * 4) = hn;
  __syncthreads();
  float mine = 0.f;
  for (int tt = 0; tt < T_; tt++) {
    const float4 p4 = *(const float4*)(wq_s + tt * H_ + l * 4);
    float p = hn.x * p4.x + hn.y * p4.y + hn.z * p4.z + hn.w * p4.w;
    p = wsum(p);
    if (l == tt) mine = p + bqt[l];
  }
  float s = (l < T_) ? mine : -1e30f;
  const float m = wmaxr(s);
  const float e = (l < T_) ? expf(s - m) : 0.f;
  const float su = wsum(e);
  if (l < T_) need[r * T_ + l] = e / su;
}

// ---------- step 0: scores, argmax, covered from chosen row ----------
__global__ __launch_bounds__(256)
void score0_kernel(const float* __restrict__ h, const float* __restrict__ se,
                   const float* __restrict__ cn, const float* __restrict__ pro,
                   float* __restrict__ covered, float* __restrict__ chosen,
                   float* __restrict__ logits, float* __restrict__ preds)
{
  __shared__ __align__(16) float hs_s[H_];
  __shared__ __align__(16) float cr_s[H_];
  __shared__ float part_s[T_ * 16];
  __shared__ float sc_s[K_];
  __shared__ float rd_s[4];
  __shared__ int idx_s;
  const int b = blockIdx.x, t = threadIdx.x;
  const int w = t >> 6, l = t & 63;

  const float hv = h[(size_t)b * H_ + t] + se[t];
  const float ss = wsum(hv * hv);
  if (l == 0) rd_s[w] = ss;
  __syncthreads();
  const float n = fmaxf(sqrtf(rd_s[0] + rd_s[1] + rd_s[2] + rd_s[3]), 1e-12f);
  hs_s[t] = hv / n;
  __syncthreads();

  const float4 hf = *(const float4*)(hs_s + l * 4);
#pragma unroll
  for (int cc = 0; cc < 8; cc++) {
    const int c = w * 8 + cc;
    const float4 cv = *(const float4*)(cn + ((size_t)b * K_ + c) * H_ + l * 4);
    float p = wsum(dot4(cv, hf));
    if (l == 0) sc_s[c] = p * 10.f;
  }
  __syncthreads();
  if (w == 0) {
    float s = (l < K_) ? sc_s[l] : -1e30f;
    int bi = (l < K_) ? l : K_;
#pragma unroll
    for (int o = 32; o; o >>= 1) {
      const float s2 = __shfl_xor(s, o);
      const int i2 = __shfl_xor(bi, o);
      if (s2 > s || (s2 == s && i2 < bi)) { s = s2; bi = i2; }
    }
    if (l == 0) idx_s = bi;
  }
  __syncthreads();
  const int idx = idx_s;
  if (t < K_) logits[(size_t)b * (S_ * K_) + t] = sc_s[t];
  if (t == 0) preds[(size_t)b * S_] = (float)idx;

  const float crv = cn[((size_t)b * K_ + idx) * H_ + t];
  cr_s[t] = crv;
  chosen[(size_t)b * H_ + t] = crv;
  __syncthreads();
  {
    const int tt = t & 15, ch = t >> 4;
    float p = 0.f;
#pragma unroll
    for (int j = 0; j < 16; j++)
      p = fmaf(cr_s[ch * 16 + j], pro[tt * H_ + ch * 16 + j], p);
    part_s[tt * 16 + ch] = p;
  }
  __syncthreads();
  if (t < 16) {
    float d = 0.f;
#pragma unroll
    for (int ch = 0; ch < 16; ch++) d += part_s[t * 16 + ch];
    float mx = d;
    mx = fmaxf(mx, __shfl_xor(mx, 1)); mx = fmaxf(mx, __shfl_xor(mx, 2));
    mx = fmaxf(mx, __shfl_xor(mx, 4)); mx = fmaxf(mx, __shfl_xor(mx, 8));
    const float e = expf(d - mx);
    float su = e;
    su += __shfl_xor(su, 1); su += __shfl_xor(su, 2);
    su += __shfl_xor(su, 4); su += __shfl_xor(su, 8);
    covered[(size_t)b * T_ + t] = fminf(e / su, 1.f);
  }
}

// ---------- step 1: GRU + scores + topic gain + argmax ----------
__global__ __launch_bounds__(256)
void score1_kernel(const float* __restrict__ gi, const float* __restrict__ gh,
                   const float* __restrict__ h,  const float* __restrict__ se,
                   const float* __restrict__ cn, const float* __restrict__ pro,
                   const float* __restrict__ need, const float* __restrict__ clam,
                   const float* __restrict__ covered,
                   float* __restrict__ logits, float* __restrict__ preds)
{
  __shared__ __align__(16) float cn_s[K_ * 260];
  __shared__ __align__(16) float pro_s[T_ * 260];
  __shared__ __align__(16) float hs_s[H_];
  __shared__ float gd_s[K_ * T_];
  __shared__ float gain_s[K_];
  __shared__ float nu_s[T_], sc_s[K_], rd_s[4], rd2_s[4];
  const int b = blockIdx.x, t = threadIdx.x;
  const int w = t >> 6, l = t & 63;

  const size_t o = (size_t)b * (3 * H_);
  const float ir = gi[o + t], iz = gi[o + 256 + t], ig = gi[o + 512 + t];
  const float hr = gh[o + t], hz = gh[o + 256 + t], hg = gh[o + 512 + t];
  const float hv = h[(size_t)b * H_ + t];
  const float rr = 1.f / (1.f + expf(-(ir + hr)));
  const float zz = 1.f / (1.f + expf(-(iz + hz)));
  const float nn = tanhf(ig + rr * hg);
  const float x = (1.f - zz) * nn + zz * hv;
  const float ss = wsum(x * x);
  if (l == 0) rd_s[w] = ss;

  {
    const float4* cng = (const float4*)(cn + (size_t)b * K_ * H_);
    float4* cns4 = (float4*)cn_s;
    for (int i = t; i < 2048; i += 256) cns4[(i >> 6) * 65 + (i & 63)] = cng[i];
    const float4* prg = (const float4*)pro;
    float4* prs4 = (float4*)pro_s;
    for (int i = t; i < 1024; i += 256) prs4[(i >> 6) * 65 + (i & 63)] = prg[i];
  }
  if (t < T_)
    nu_s[t] = need[(size_t)b * T_ + t] * fminf(fmaxf(1.f - covered[(size_t)b * T_ + t], 0.f), 1.f);
  __syncthreads();
  const float n1 = fmaxf(sqrtf(rd_s[0] + rd_s[1] + rd_s[2] + rd_s[3]), 1e-12f);
  const float y = x / n1 + se[H_ + t];
  const float ss2 = wsum(y * y);
  if (l == 0) rd2_s[w] = ss2;
  __syncthreads();
  const float n2 = fmaxf(sqrtf(rd2_s[0] + rd2_s[1] + rd2_s[2] + rd2_s[3]), 1e-12f);
  hs_s[t] = y / n2;
  __syncthreads();

  const float4* cn_s4 = (const float4*)cn_s;
  const float4* pro_s4 = (const float4*)pro_s;
  const float4 hf = *(const float4*)(hs_s + l * 4);
#pragma unroll
  for (int cc = 0; cc < 8; cc++) {
    const int c = w * 8 + cc;
    const float4 cv = cn_s4[c * 65 + l];
    float p = wsum(dot4(cv, hf));
    if (l == 0) sc_s[c] = p * 10.f;
  }
#pragma unroll
  for (int pr = 0; pr < 2; pr++) {
    const int idx2 = t + pr * 256;
    const int c = idx2 >> 4, tt = idx2 & 15;
    float d = 0.f;
#pragma unroll 8
    for (int j = 0; j < 64; j++)
      d += dot4(cn_s4[c * 65 + j], pro_s4[tt * 65 + j]);
    gd_s[idx2] = d;
  }
  __syncthreads();
  if (t < K_) {
    float mx = -1e30f;
#pragma unroll
    for (int tt = 0; tt < T_; tt++) mx = fmaxf(mx, gd_s[t * T_ + tt]);
    float su = 0.f, ga = 0.f;
#pragma unroll
    for (int tt = 0; tt < T_; tt++) {
      const float e = expf(gd_s[t * T_ + tt] - mx);
      su += e; ga = fmaf(nu_s[tt], e, ga);
    }
    gain_s[t] = ga / su;
  }
  const int i0 = (int)preds[(size_t)b * S_];
  __syncthreads();
  if (w == 0) {
    const float lam = log1pf(expf(clam[0]));
    float s = (l < K_) ? sc_s[l] + lam * gain_s[l] : -1e30f;
    if (l < K_ && l == i0) s = -100.f;
    if (l < K_) logits[(size_t)b * (S_ * K_) + K_ + l] = s;
    int bi = (l < K_) ? l : K_;
    float sm = s;
#pragma unroll
    for (int o2 = 32; o2; o2 >>= 1) {
      const float s2 = __shfl_xor(sm, o2);
      const int i2 = __shfl_xor(bi, o2);
      if (s2 > sm || (s2 == sm && i2 < bi)) { sm = s2; bi = i2; }
    }
    if (l == 0) preds[(size_t)b * S_ + 1] = (float)bi;
  }
}

extern "C" void kernel_launch(void* const* d_in, const int* in_sizes, int n_in,
                              void* d_out, int out_size, void* d_ws, size_t ws_size,
                              hipStream_t stream)
{
  const float* query_emb = (const float*)d_in[0];
  const float* cand_emb  = (const float*)d_in[1];
  const float* W_in = (const float*)d_in[2];
  const float* Wq_a = (const float*)d_in[3];
  const float* Wk_a = (const float*)d_in[4];
  const float* Wv_a = (const float*)d_in[5];
  const float* bq_a = (const float*)d_in[6];
  const float* bk_a = (const float*)d_in[7];
  const float* bv_a = (const float*)d_in[8];
  const float* Wo_a = (const float*)d_in[9];
  const float* bo_a = (const float*)d_in[10];
  const float* ln_w = (const float*)d_in[11];
  const float* ln_b = (const float*)d_in[12];
  const float* Wq   = (const float*)d_in[13];
  const float* Wc   = (const float*)d_in[14];
  const float* W_ih = (const float*)d_in[15];
  const float* W_hh = (const float*)d_in[16];
  const float* b_ih = (const float*)d_in[17];
  const float* b_hh = (const float*)d_in[18];
  const float* step_emb = (const float*)d_in[19];
  const float* tpro = (const float*)d_in[20];
  const float* Wqt  = (const float*)d_in[21];
  const float* bqt  = (const float*)d_in[22];
  const float* clam = (const float*)d_in[23];

  float* ws = (float*)d_ws;
  size_t o = 0;
  float* WkinT = ws + o; o += (size_t)D_ * H_;
  float* Wv_in = ws + o; o += (size_t)H_ * D_;
  ushort* BhW  = (ushort*)(ws + o); o += 98304;
  ushort* BlW  = (ushort*)(ws + o); o += 98304;
  float* pro   = ws + o; o += (size_t)T_ * H_;
  float* Bqk   = ws + o; o += (size_t)D_ * H_;
  float* bqk   = ws + o; o += 1024;
  float* Wvo   = ws + o; o += (size_t)H_ * D_;
  float* bvo   = ws + o; o += 256;
  float* Wqp   = ws + o; o += (size_t)H_ * H_;
  float* bqp   = ws + o; o += 256;
  float* vqbk  = ws + o; o += 256;
  float* qcst  = ws + o; o += 4;
  ushort* WintH = (ushort*)(ws + o); o += 98304;
  ushort* WintL = (ushort*)(ws + o); o += 98304;
  ushort* BqktH = (ushort*)(ws + o); o += 98304;
  ushort* BqktL = (ushort*)(ws + o); o += 98304;
  ushort* WvotH = (ushort*)(ws + o); o += 98304;
  ushort* WvotL = (ushort*)(ws + o); o += 98304;
  ushort* WqptH = (ushort*)(ws + o); o += 32768;
  ushort* WqptL = (ushort*)(ws + o); o += 32768;
  ushort* WihtH = (ushort*)(ws + o); o += 98304;
  ushort* WihtL = (ushort*)(ws + o); o += 98304;
  ushort* WhhtH = (ushort*)(ws + o); o += 98304;
  ushort* WhhtL = (ushort*)(ws + o); o += 98304;
  float* qr    = ws + o; o += (size_t)B_ * H_;
  float* qkv   = ws + o; o += (size_t)B_ * D_;   // later: gi
  float* wce   = ws + o; o += (size_t)B_ * D_;   // later: gh
  float* ctxb  = ws + o; o += (size_t)B_ * H_;   // hraw
  float* xhat  = ws + o; o += (size_t)B_ * H_;
  float* h     = ws + o; o += (size_t)B_ * H_;
  float* need  = ws + o; o += (size_t)B_ * T_;
  float* cn    = ws + o; o += (size_t)B_ * K_ * H_;
  float* cov   = ws + o; o += (size_t)B_ * T_;
  float* chosen= ws + o; o += (size_t)B_ * H_;

  float* out_logits = (float*)d_out;
  float* out_preds  = (float*)d_out + (size_t)B_ * S_ * K_;

  // weight folding + tiling
  fold_kernel<<<dim3(H_, 3), 256, 0, stream>>>(Wk_a, Wv_a, Wc, W_in, WkinT, Wv_in, BhW, BlW);
  proto_kernel<<<1, 256, 0, stream>>>(tpro, pro);
  fold2_kernel<<<D_, 256, 0, stream>>>(Wq_a, bq_a, bk_a, Wo_a, bo_a, bv_a, Wq, ln_w, ln_b,
                                       WkinT, Wv_in, Bqk, bqk, Wvo, bvo, Wqp, bqp, vqbk, qcst);
  TileJobs jobs;
  jobs.j[0] = {W_in, WintH, WintL, 16, 768, 256};
  jobs.j[1] = {Bqk,  BqktH, BqktL, 48, 256, 768};
  jobs.j[2] = {Wvo,  WvotH, WvotL, 16, 768, 256};
  jobs.j[3] = {Wqp,  WqptH, WqptL, 16, 256, 256};
  jobs.j[4] = {W_ih, WihtH, WihtL, 48, 256, 768};
  jobs.j[5] = {W_hh, WhhtH, WhhtL, 48, 256, 768};
  tile_all<<<dim3(768, 6), 256, 0, stream>>>(jobs);

  // query path
  gemm_bf<24, 16, false><<<dim3(B_ / 128, 4), 256, 0, stream>>>(query_emb, WintH, WintL, nullptr, qr);
  gemm_bf<8, 48, true><<<dim3(B_ / 128, 12), 256, 0, stream>>>(qr, BqktH, BqktL, bqk, qkv);

  // candidate path + fused attention
  gemm_cn_attn<<<(B_ * K_) / 64, 256, 0, stream>>>(cand_emb, BhW, BlW, qkv, qr, vqbk, qcst, cn, wce);

  // ctx gemm + residual + LN fused
  gemm_ctx_ln<<<B_ / 32, 256, 0, stream>>>(wce, WvotH, WvotL, bvo, qr, xhat);
  gemm_bf<8, 16, true><<<dim3(B_ / 128, 4), 256, 0, stream>>>(xhat, WqptH, WqptL, bqp, ctxb);  // hraw
  h_post<<<B_ / 4, 256, 0, stream>>>(ctxb, Wqt, bqt, h, need);

  // step 0 (scores + covered + chosen)
  score0_kernel<<<B_, 256, 0, stream>>>(h, step_emb, cn, pro, cov, chosen, out_logits, out_preds);
  // GRU gates
  gemm_bf<8, 48, true><<<dim3(B_ / 128, 12), 256, 0, stream>>>(chosen, WihtH, WihtL, b_ih, qkv);  // gi
  gemm_bf<8, 48, true><<<dim3(B_ / 128, 12), 256, 0, stream>>>(h, WhhtH, WhhtL, b_hh, wce);       // gh
  // step 1 (GRU + scores + topic gain)
  score1_kernel<<<B_, 256, 0, stream>>>(qkv, wce, h, step_emb, cn, pro, need, clam, cov,
                                        out_logits, out_preds);
}

// Round 11
// 884.240 us; speedup vs baseline: 1.3772x; 1.3772x over previous
//
#include <hip/hip_runtime.h>
#include <math.h>

#define B_ 8192
#define K_ 32
#define D_ 768
#define H_ 256
#define T_ 16
#define S_ 2

typedef unsigned int uint;
typedef unsigned short ushort;
typedef __attribute__((ext_vector_type(8))) short bf16x8;
typedef __attribute__((ext_vector_type(4))) float f32x4;

// ---------- wave (64-lane) reductions ----------
__device__ __forceinline__ float wsum(float v) {
  v += __shfl_xor(v, 32); v += __shfl_xor(v, 16); v += __shfl_xor(v, 8);
  v += __shfl_xor(v, 4);  v += __shfl_xor(v, 2);  v += __shfl_xor(v, 1);
  return v;
}
__device__ __forceinline__ float wmaxr(float v) {
  v = fmaxf(v, __shfl_xor(v, 32)); v = fmaxf(v, __shfl_xor(v, 16));
  v = fmaxf(v, __shfl_xor(v, 8));  v = fmaxf(v, __shfl_xor(v, 4));
  v = fmaxf(v, __shfl_xor(v, 2));  v = fmaxf(v, __shfl_xor(v, 1));
  return v;
}

// split fp32 -> (hi bf16 trunc, lo bf16 trunc of exact remainder), packed 2/uint
__device__ __forceinline__ void split4(const float4 f, uint2& h, uint2& lo) {
  const uint ux = __float_as_uint(f.x), uy = __float_as_uint(f.y);
  const uint uz = __float_as_uint(f.z), uw = __float_as_uint(f.w);
  h.x = (uy & 0xFFFF0000u) | (ux >> 16);
  h.y = (uw & 0xFFFF0000u) | (uz >> 16);
  const float rx = f.x - __uint_as_float(ux & 0xFFFF0000u);
  const float ry = f.y - __uint_as_float(uy & 0xFFFF0000u);
  const float rz = f.z - __uint_as_float(uz & 0xFFFF0000u);
  const float rw = f.w - __uint_as_float(uw & 0xFFFF0000u);
  lo.x = (__float_as_uint(ry) & 0xFFFF0000u) | (__float_as_uint(rx) >> 16);
  lo.y = (__float_as_uint(rw) & 0xFFFF0000u) | (__float_as_uint(rz) >> 16);
}

__device__ __forceinline__ float dot4(const float4 a, const float4 b) {
  float s = a.x * b.x;
  s = fmaf(a.y, b.y, s); s = fmaf(a.z, b.z, s); s = fmaf(a.w, b.w, s);
  return s;
}

// B frag tiling (NB = N/16): elem(n,k) -> ((ks*NB + nb)*64 + (nl | kc<<4))*8 + kb

// ---------- fold stage 1: WkinT fp32, Wv_in fp32, Wc_in -> hi/lo bf16 frag-tiled (NB=16) ----------
__global__ __launch_bounds__(256)
void fold_kernel(const float* __restrict__ Wk_a, const float* __restrict__ Wv_a,
                 const float* __restrict__ Wc,  const float* __restrict__ W_in,
                 float* __restrict__ WkinT, float* __restrict__ Wv_in,
                 ushort* __restrict__ Bh, ushort* __restrict__ Bl)
{
  const int i = blockIdx.x;
  const int m = blockIdx.y;
  const float* Wx = (m == 0) ? Wk_a : ((m == 1) ? Wv_a : Wc);
  const int t = threadIdx.x;
  float a0 = 0.f, a1 = 0.f, a2 = 0.f;
  for (int k = 0; k < H_; k++) {
    const float wv = Wx[i * H_ + k];
    const float* row = W_in + (size_t)k * D_;
    a0 = fmaf(wv, row[t], a0);
    a1 = fmaf(wv, row[t + 256], a1);
    a2 = fmaf(wv, row[t + 512], a2);
  }
  if (m == 0) {
    WkinT[(size_t)t * H_ + i] = a0;
    WkinT[(size_t)(t + 256) * H_ + i] = a1;
    WkinT[(size_t)(t + 512) * H_ + i] = a2;
  } else if (m == 1) {
    float* o = Wv_in + (size_t)i * D_;
    o[t] = a0; o[t + 256] = a1; o[t + 512] = a2;
  } else {
    const float vals[3] = {a0, a1, a2};
#pragma unroll
    for (int j = 0; j < 3; j++) {
      const int k = t + j * 256;
      const float v = vals[j];
      const int idx = (((k >> 5) * 16 + (i >> 4)) * 64 + ((i & 15) | (((k >> 3) & 3) << 4))) * 8 + (k & 7);
      const uint u = __float_as_uint(v);
      Bh[idx] = (ushort)(u >> 16);
      const float rr = v - __uint_as_float(u & 0xFFFF0000u);
      Bl[idx] = (ushort)(__float_as_uint(rr) >> 16);
    }
  }
}

// ---------- all weight tilings in one launch ----------
struct TileJob { const float* W; ushort* Bh; ushort* Bl; int NB; int K; int rows; };
struct TileJobs { TileJob j[6]; };

__global__ __launch_bounds__(256)
void tile_all(TileJobs jobs)
{
  const TileJob J = jobs.j[blockIdx.y];
  const int n = blockIdx.x;
  if (n >= J.rows) return;
  const int t = threadIdx.x;
  for (int k = t; k < J.K; k += 256) {
    const float v = J.W[(size_t)n * J.K + k];
    const int idx = (((k >> 5) * J.NB + (n >> 4)) * 64 + ((n & 15) | (((k >> 3) & 3) << 4))) * 8 + (k & 7);
    const uint u = __float_as_uint(v);
    J.Bh[idx] = (ushort)(u >> 16);
    const float rr = v - __uint_as_float(u & 0xFFFF0000u);
    J.Bl[idx] = (ushort)(__float_as_uint(rr) >> 16);
  }
}

// ---------- l2-normalize topic prototypes ----------
__global__ __launch_bounds__(256)
void proto_kernel(const float* __restrict__ tpro, float* __restrict__ pro)
{
  const int w = threadIdx.x >> 6, l = threadIdx.x & 63;
  for (int r = w; r < T_; r += 4) {
    const float4 v = *(const float4*)(tpro + (size_t)r * H_ + l * 4);
    const float n = fmaxf(sqrtf(wsum(v.x * v.x + v.y * v.y + v.z * v.z + v.w * v.w)), 1e-12f);
    float4 o; o.x = v.x / n; o.y = v.y / n; o.z = v.z / n; o.w = v.w / n;
    *(float4*)(pro + (size_t)r * H_ + l * 4) = o;
  }
}

// ---------- fold stage 2: attention/query-path weight folds ----------
__global__ __launch_bounds__(256)
void fold2_kernel(const float* __restrict__ Wq_a, const float* __restrict__ bq_a,
                  const float* __restrict__ bk_a, const float* __restrict__ Wo_a,
                  const float* __restrict__ bo_a, const float* __restrict__ bv_a,
                  const float* __restrict__ Wq,   const float* __restrict__ ln_w,
                  const float* __restrict__ ln_b, const float* __restrict__ WkinT,
                  const float* __restrict__ Wv_in,
                  float* __restrict__ Bqk, float* __restrict__ bqk,
                  float* __restrict__ Wvo, float* __restrict__ bvo,
                  float* __restrict__ Wqp, float* __restrict__ bqp,
                  float* __restrict__ vqbk, float* __restrict__ qcst)
{
  __shared__ float rd_s[4];
  const int n = blockIdx.x, t = threadIdx.x, w = t >> 6, l = t & 63;
  float s = 0.f;
  for (int hh = 0; hh < H_; hh++)
    s = fmaf(Wq_a[hh * H_ + t], WkinT[(size_t)n * H_ + hh], s);
  Bqk[(size_t)n * H_ + t] = s;
  float p = bq_a[t] * WkinT[(size_t)n * H_ + t];
  p = wsum(p);
  if (l == 0) rd_s[w] = p;
  __syncthreads();
  if (t == 0) bqk[n] = rd_s[0] + rd_s[1] + rd_s[2] + rd_s[3];
  if (n < H_) {
    float a0 = 0.f, a1 = 0.f, a2 = 0.f;
    for (int hh = 0; hh < H_; hh++) {
      const float wo = Wo_a[n * H_ + hh];
      const float* rowv = Wv_in + (size_t)hh * D_;
      a0 = fmaf(wo, rowv[t], a0);
      a1 = fmaf(wo, rowv[t + 256], a1);
      a2 = fmaf(wo, rowv[t + 512], a2);
    }
    Wvo[(size_t)n * D_ + t] = a0;
    Wvo[(size_t)n * D_ + t + 256] = a1;
    Wvo[(size_t)n * D_ + t + 512] = a2;
    float pb = Wo_a[n * H_ + t] * bv_a[t];
    pb = wsum(pb);
    __syncthreads();
    if (l == 0) rd_s[w] = pb;
    __syncthreads();
    if (t == 0) bvo[n] = rd_s[0] + rd_s[1] + rd_s[2] + rd_s[3] + bo_a[n];
    Wqp[n * H_ + t] = Wq[n * H_ + t] * ln_w[t];
    float pq = Wq[n * H_ + t] * ln_b[t];
    pq = wsum(pq);
    __syncthreads();
    if (l == 0) rd_s[w] = pq;
    __syncthreads();
    if (t == 0) bqp[n] = rd_s[0] + rd_s[1] + rd_s[2] + rd_s[3];
  }
  if (n == 0) {
    float sv = 0.f;
    for (int hh = 0; hh < H_; hh++) sv = fmaf(bk_a[hh], Wq_a[hh * H_ + t], sv);
    vqbk[t] = sv;
    float pc = bq_a[t] * bk_a[t];
    pc = wsum(pc);
    __syncthreads();
    if (l == 0) rd_s[w] = pc;
    __syncthreads();
    if (t == 0) qcst[0] = rd_s[0] + rd_s[1] + rd_s[2] + rd_s[3];
  }
}

// ---------- fused gemm_cn + cross-attention (R6/R7 verified: LDS A-dbuf, B-hoisted) ----------
__global__ __launch_bounds__(256, 3)
void gemm_cn_attn(const float* __restrict__ A, const ushort* __restrict__ Bh,
                  const ushort* __restrict__ Bl, const float* __restrict__ qkv,
                  const float* __restrict__ qr, const float* __restrict__ vqbk,
                  const float* __restrict__ qcst, float* __restrict__ C,
                  float* __restrict__ wce)
{
  __shared__ __align__(16) ushort AhS[2][2048], AlS[2][2048];
  __shared__ __align__(16) float4 qkv_s[384];
  __shared__ float sc_s[64], at_s[64], qbk_s[2];
  __shared__ float rsq[64][4];
  const int t = threadIdx.x, l = t & 63, w = t >> 6;
  const int r = t >> 2, kc = t & 3;
  const int tb = t >> 7;
  const float* Ag = A + ((size_t)blockIdx.x * 64 + r) * 768 + kc * 8;
  const int aslot = ((r >> 4) * 64 + ((r & 15) | (kc << 4))) * 8;
  const ushort* Bhb = Bh + ((w * 4) * 64 + l) * 8;
  const ushort* Blb = Bl + ((w * 4) * 64 + l) * 8;

  for (int i = t; i < 384; i += 256)
    qkv_s[i] = ((const float4*)qkv)[(size_t)blockIdx.x * 384 + i];
  if (w < 2) {
    const float4 q4 = ((const float4*)qr)[((size_t)blockIdx.x * 2 + w) * 64 + l];
    const float4 v4 = ((const float4*)vqbk)[l];
    float p = wsum(dot4(q4, v4));
    if (l == 0) qbk_s[w] = p + qcst[0];
  }

  f32x4 acc[4][4];
#pragma unroll
  for (int i = 0; i < 4; i++)
#pragma unroll
    for (int j = 0; j < 4; j++) acc[i][j] = (f32x4)0.f;

  float sc = 0.f;
  float4 f0 = *(const float4*)(Ag);
  float4 f1 = *(const float4*)(Ag + 4);
  __syncthreads();
  sc += dot4(f0, qkv_s[tb * 192 + kc * 2]) + dot4(f1, qkv_s[tb * 192 + kc * 2 + 1]);
  {
    uint2 ha, la, hb, lb;
    split4(f0, ha, la); split4(f1, hb, lb);
    *(uint4*)&AhS[0][aslot] = make_uint4(ha.x, ha.y, hb.x, hb.y);
    *(uint4*)&AlS[0][aslot] = make_uint4(la.x, la.y, lb.x, lb.y);
  }
  f0 = *(const float4*)(Ag + 32);
  f1 = *(const float4*)(Ag + 36);
  __syncthreads();

#pragma unroll 2
  for (int ks = 0; ks < 24; ks++) {
    const int cur = ks & 1;
    uint4 bhv[4], blv[4];
#pragma unroll
    for (int ni = 0; ni < 4; ni++) {
      bhv[ni] = *(const uint4*)(Bhb + ks * 8192 + ni * 512);
      blv[ni] = *(const uint4*)(Blb + ks * 8192 + ni * 512);
    }
    if (ks < 23) {
      sc += dot4(f0, qkv_s[tb * 192 + (ks + 1) * 8 + kc * 2]) +
            dot4(f1, qkv_s[tb * 192 + (ks + 1) * 8 + kc * 2 + 1]);
      uint2 ha, la, hb, lb;
      split4(f0, ha, la); split4(f1, hb, lb);
      *(uint4*)&AhS[cur ^ 1][aslot] = make_uint4(ha.x, ha.y, hb.x, hb.y);
      *(uint4*)&AlS[cur ^ 1][aslot] = make_uint4(la.x, la.y, lb.x, lb.y);
      if (ks < 22) {
        f0 = *(const float4*)(Ag + (ks + 2) * 32);
        f1 = *(const float4*)(Ag + (ks + 2) * 32 + 4);
      }
    }
#pragma unroll
    for (int mi = 0; mi < 4; mi++) {
      const bf16x8 ah = *(const bf16x8*)&AhS[cur][(mi * 64 + l) * 8];
      const bf16x8 al = *(const bf16x8*)&AlS[cur][(mi * 64 + l) * 8];
#pragma unroll
      for (int ni = 0; ni < 4; ni++) {
        const bf16x8 bhf = *(const bf16x8*)&bhv[ni];
        const bf16x8 blf = *(const bf16x8*)&blv[ni];
        acc[mi][ni] = __builtin_amdgcn_mfma_f32_16x16x32_bf16(ah, bhf, acc[mi][ni], 0, 0, 0);
        acc[mi][ni] = __builtin_amdgcn_mfma_f32_16x16x32_bf16(al, bhf, acc[mi][ni], 0, 0, 0);
        acc[mi][ni] = __builtin_amdgcn_mfma_f32_16x16x32_bf16(ah, blf, acc[mi][ni], 0, 0, 0);
      }
    }
    __syncthreads();
  }

  sc += __shfl_xor(sc, 1);
  sc += __shfl_xor(sc, 2);
  if ((t & 3) == 0) sc_s[r] = sc;
  __syncthreads();
  if (w < 2) {
    float s = (l < 32) ? (sc_s[w * 32 + l] + qbk_s[w]) * (1.f / 16.f) : -1e30f;
    const float m = wmaxr(s);
    const float e = (l < 32) ? expf(s - m) : 0.f;
    const float su = wsum(e);
    if (l < 32) at_s[w * 32 + l] = e / su;
  }
  __syncthreads();
#pragma unroll
  for (int p = 0; p < 2; p++) {
    const int slot = t + p * 256;
    if (slot < 384) {
      const int tb2 = slot >= 192;
      const int idx = slot - tb2 * 192;
      const float4* cb = (const float4*)A + ((size_t)blockIdx.x * 64 + tb2 * 32) * 192 + idx;
      float4 a = make_float4(0.f, 0.f, 0.f, 0.f);
#pragma unroll 4
      for (int c = 0; c < 32; c++) {
        const float av = at_s[tb2 * 32 + c];
        const float4 f = cb[c * 192];
        a.x = fmaf(av, f.x, a.x); a.y = fmaf(av, f.y, a.y);
        a.z = fmaf(av, f.z, a.z); a.w = fmaf(av, f.w, a.w);
      }
      ((float4*)wce)[((size_t)blockIdx.x * 2 + tb2) * 192 + idx] = a;
    }
  }

#pragma unroll
  for (int mi = 0; mi < 4; mi++)
#pragma unroll
    for (int rg = 0; rg < 4; rg++) {
      float p = 0.f;
#pragma unroll
      for (int ni = 0; ni < 4; ni++) { const float v = acc[mi][ni][rg]; p = fmaf(v, v, p); }
      p += __shfl_xor(p, 1); p += __shfl_xor(p, 2); p += __shfl_xor(p, 4); p += __shfl_xor(p, 8);
      if ((l & 15) == 0) rsq[mi * 16 + (l >> 4) * 4 + rg][w] = p;
    }
  __syncthreads();
  const size_t row0 = (size_t)blockIdx.x * 64;
#pragma unroll
  for (int mi = 0; mi < 4; mi++)
#pragma unroll
    for (int rg = 0; rg < 4; rg++) {
      const int rl = mi * 16 + (l >> 4) * 4 + rg;
      const float ssum = rsq[rl][0] + rsq[rl][1] + rsq[rl][2] + rsq[rl][3];
      const float inv = 1.f / fmaxf(sqrtf(ssum), 1e-12f);
#pragma unroll
      for (int ni = 0; ni < 4; ni++)
        C[(row0 + rl) * H_ + w * 64 + ni * 16 + (l & 15)] = acc[mi][ni][rg] * inv;
    }
}

// ---------- gemm ctx + residual + LayerNorm fused: xhat = LN(wce@Wvo^T + bvo + qr) ----------
__global__ __launch_bounds__(256, 3)
void gemm_ctx_ln(const float* __restrict__ A, const ushort* __restrict__ Bh,
                 const ushort* __restrict__ Bl, const float* __restrict__ bvo,
                 const float* __restrict__ qr, float* __restrict__ xhat)
{
  __shared__ __align__(16) ushort AhS[2][2048], AlS[2][2048];
  __shared__ float red[64][4][2];
  const int t = threadIdx.x, l = t & 63, w = t >> 6;
  const int r = t >> 2, kc = t & 3;
  const float* Ag = A + ((size_t)blockIdx.x * 64 + r) * 768 + kc * 8;
  const int aslot = ((r >> 4) * 64 + ((r & 15) | (kc << 4))) * 8;
  const ushort* Bhb = Bh + ((w * 4) * 64 + l) * 8;
  const ushort* Blb = Bl + ((w * 4) * 64 + l) * 8;

  f32x4 acc[4][4];
#pragma unroll
  for (int i = 0; i < 4; i++)
#pragma unroll
    for (int j = 0; j < 4; j++) acc[i][j] = (f32x4)0.f;

  float4 f0 = *(const float4*)(Ag);
  float4 f1 = *(const float4*)(Ag + 4);
  {
    uint2 ha, la, hb, lb;
    split4(f0, ha, la); split4(f1, hb, lb);
    *(uint4*)&AhS[0][aslot] = make_uint4(ha.x, ha.y, hb.x, hb.y);
    *(uint4*)&AlS[0][aslot] = make_uint4(la.x, la.y, lb.x, lb.y);
  }
  f0 = *(const float4*)(Ag + 32);
  f1 = *(const float4*)(Ag + 36);
  __syncthreads();

#pragma unroll 2
  for (int ks = 0; ks < 24; ks++) {
    const int cur = ks & 1;
    uint4 bhv[4], blv[4];
#pragma unroll
    for (int ni = 0; ni < 4; ni++) {
      bhv[ni] = *(const uint4*)(Bhb + ks * 8192 + ni * 512);
      blv[ni] = *(const uint4*)(Blb + ks * 8192 + ni * 512);
    }
    if (ks < 23) {
      uint2 ha, la, hb, lb;
      split4(f0, ha, la); split4(f1, hb, lb);
      *(uint4*)&AhS[cur ^ 1][aslot] = make_uint4(ha.x, ha.y, hb.x, hb.y);
      *(uint4*)&AlS[cur ^ 1][aslot] = make_uint4(la.x, la.y, lb.x, lb.y);
      if (ks < 22) {
        f0 = *(const float4*)(Ag + (ks + 2) * 32);
        f1 = *(const float4*)(Ag + (ks + 2) * 32 + 4);
      }
    }
#pragma unroll
    for (int mi = 0; mi < 4; mi++) {
      const bf16x8 ah = *(const bf16x8*)&AhS[cur][(mi * 64 + l) * 8];
      const bf16x8 al = *(const bf16x8*)&AlS[cur][(mi * 64 + l) * 8];
#pragma unroll
      for (int ni = 0; ni < 4; ni++) {
        const bf16x8 bhf = *(const bf16x8*)&bhv[ni];
        const bf16x8 blf = *(const bf16x8*)&blv[ni];
        acc[mi][ni] = __builtin_amdgcn_mfma_f32_16x16x32_bf16(ah, bhf, acc[mi][ni], 0, 0, 0);
        acc[mi][ni] = __builtin_amdgcn_mfma_f32_16x16x32_bf16(al, bhf, acc[mi][ni], 0, 0, 0);
        acc[mi][ni] = __builtin_amdgcn_mfma_f32_16x16x32_bf16(ah, blf, acc[mi][ni], 0, 0, 0);
      }
    }
    __syncthreads();
  }

  const size_t row0 = (size_t)blockIdx.x * 64;
#pragma unroll
  for (int mi = 0; mi < 4; mi++)
#pragma unroll
    for (int rg = 0; rg < 4; rg++) {
      const int rl = mi * 16 + (l >> 4) * 4 + rg;
      float sx = 0.f, sxx = 0.f;
#pragma unroll
      for (int ni = 0; ni < 4; ni++) {
        const int col = w * 64 + ni * 16 + (l & 15);
        const float x = acc[mi][ni][rg] + bvo[col] + qr[(row0 + rl) * H_ + col];
        acc[mi][ni][rg] = x;
        sx += x; sxx = fmaf(x, x, sxx);
      }
      sx += __shfl_xor(sx, 1); sx += __shfl_xor(sx, 2); sx += __shfl_xor(sx, 4); sx += __shfl_xor(sx, 8);
      sxx += __shfl_xor(sxx, 1); sxx += __shfl_xor(sxx, 2); sxx += __shfl_xor(sxx, 4); sxx += __shfl_xor(sxx, 8);
      if ((l & 15) == 0) { red[rl][w][0] = sx; red[rl][w][1] = sxx; }
    }
  __syncthreads();
#pragma unroll
  for (int mi = 0; mi < 4; mi++)
#pragma unroll
    for (int rg = 0; rg < 4; rg++) {
      const int rl = mi * 16 + (l >> 4) * 4 + rg;
      const float SX = red[rl][0][0] + red[rl][1][0] + red[rl][2][0] + red[rl][3][0];
      const float SXX = red[rl][0][1] + red[rl][1][1] + red[rl][2][1] + red[rl][3][1];
      const float mu = SX * (1.f / H_);
      const float var = SXX * (1.f / H_) - mu * mu;
      const float isd = 1.f / sqrtf(var + 1e-5f);
#pragma unroll
      for (int ni = 0; ni < 4; ni++)
        xhat[(row0 + rl) * H_ + w * 64 + ni * 16 + (l & 15)] = (acc[mi][ni][rg] - mu) * isd;
    }
}

// ---------- generic split-bf16 MFMA GEMM: C[M,N] = A[M,K]*B^T (+bias), B pre-tiled ----------
template<int NKS, int NB, bool BIAS>
__global__ __launch_bounds__(256)
void gemm_bf(const float* __restrict__ A, const ushort* __restrict__ Bh,
             const ushort* __restrict__ Bl, const float* __restrict__ bias,
             float* __restrict__ C)
{
  __shared__ __align__(16) ushort AhS[2][4096], AlS[2][4096];
  const int t = threadIdx.x, l = t & 63, w = t >> 6;
  const int wr = w >> 1, wc = w & 1;
  const int Kd = NKS * 32, N = NB * 16;
  const int r = t >> 1, kc0 = (t & 1) * 2;
  const float* Ag = A + ((size_t)blockIdx.x * 128 + r) * Kd + kc0 * 8;
  const int aslot0 = ((r >> 4) * 64 + ((r & 15) | (kc0 << 4))) * 8;
  const int aslot1 = aslot0 + 128;
  const int nb0 = blockIdx.y * 4 + wc * 2;
  const ushort* Bhb = Bh + (nb0 * 64 + l) * 8;
  const ushort* Blb = Bl + (nb0 * 64 + l) * 8;

  f32x4 acc[4][2];
#pragma unroll
  for (int i = 0; i < 4; i++)
#pragma unroll
    for (int j = 0; j < 2; j++) acc[i][j] = (f32x4)0.f;

  float4 f0 = *(const float4*)(Ag);
  float4 f1 = *(const float4*)(Ag + 4);
  float4 f2 = *(const float4*)(Ag + 8);
  float4 f3 = *(const float4*)(Ag + 12);
  {
    uint2 ha, la, hb, lb;
    split4(f0, ha, la); split4(f1, hb, lb);
    *(uint4*)&AhS[0][aslot0] = make_uint4(ha.x, ha.y, hb.x, hb.y);
    *(uint4*)&AlS[0][aslot0] = make_uint4(la.x, la.y, lb.x, lb.y);
    split4(f2, ha, la); split4(f3, hb, lb);
    *(uint4*)&AhS[0][aslot1] = make_uint4(ha.x, ha.y, hb.x, hb.y);
    *(uint4*)&AlS[0][aslot1] = make_uint4(la.x, la.y, lb.x, lb.y);
  }
  f0 = *(const float4*)(Ag + 32); f1 = *(const float4*)(Ag + 36);
  f2 = *(const float4*)(Ag + 40); f3 = *(const float4*)(Ag + 44);
  __syncthreads();

#pragma unroll 2
  for (int ks = 0; ks < NKS; ks++) {
    const int cur = ks & 1;
    if (ks < NKS - 1) {
      uint2 ha, la, hb, lb;
      split4(f0, ha, la); split4(f1, hb, lb);
      *(uint4*)&AhS[cur ^ 1][aslot0] = make_uint4(ha.x, ha.y, hb.x, hb.y);
      *(uint4*)&AlS[cur ^ 1][aslot0] = make_uint4(la.x, la.y, lb.x, lb.y);
      split4(f2, ha, la); split4(f3, hb, lb);
      *(uint4*)&AhS[cur ^ 1][aslot1] = make_uint4(ha.x, ha.y, hb.x, hb.y);
      *(uint4*)&AlS[cur ^ 1][aslot1] = make_uint4(la.x, la.y, lb.x, lb.y);
      if (ks < NKS - 2) {
        f0 = *(const float4*)(Ag + (ks + 2) * 32);
        f1 = *(const float4*)(Ag + (ks + 2) * 32 + 4);
        f2 = *(const float4*)(Ag + (ks + 2) * 32 + 8);
        f3 = *(const float4*)(Ag + (ks + 2) * 32 + 12);
      }
    }
#pragma unroll
    for (int mi = 0; mi < 4; mi++) {
      const bf16x8 ah = *(const bf16x8*)&AhS[cur][((wr * 4 + mi) * 64 + l) * 8];
      const bf16x8 al = *(const bf16x8*)&AlS[cur][((wr * 4 + mi) * 64 + l) * 8];
#pragma unroll
      for (int ni = 0; ni < 2; ni++) {
        const bf16x8 bhf = *(const bf16x8*)(Bhb + ks * (NB * 512) + ni * 512);
        const bf16x8 blf = *(const bf16x8*)(Blb + ks * (NB * 512) + ni * 512);
        acc[mi][ni] = __builtin_amdgcn_mfma_f32_16x16x32_bf16(ah, bhf, acc[mi][ni], 0, 0, 0);
        acc[mi][ni] = __builtin_amdgcn_mfma_f32_16x16x32_bf16(al, bhf, acc[mi][ni], 0, 0, 0);
        acc[mi][ni] = __builtin_amdgcn_mfma_f32_16x16x32_bf16(ah, blf, acc[mi][ni], 0, 0, 0);
      }
    }
    __syncthreads();
  }

  const size_t row0 = (size_t)blockIdx.x * 128 + wr * 64;
  const int col0 = blockIdx.y * 64 + wc * 32;
#pragma unroll
  for (int mi = 0; mi < 4; mi++)
#pragma unroll
    for (int ni = 0; ni < 2; ni++) {
      const int col = col0 + ni * 16 + (l & 15);
      const float bb = BIAS ? bias[col] : 0.f;
#pragma unroll
      for (int rg = 0; rg < 4; rg++) {
        const size_t row = row0 + mi * 16 + (l >> 4) * 4 + rg;
        C[row * N + col] = acc[mi][ni][rg] + bb;
      }
    }
}

// ---------- h = l2n(hraw); need = softmax(h@Wqt^T + bqt) ----------
__global__ __launch_bounds__(256)
void h_post(const float* __restrict__ hraw, const float* __restrict__ Wqt,
            const float* __restrict__ bqt, float* __restrict__ h, float* __restrict__ need)
{
  __shared__ float wq_s[T_ * H_];
  for (int i = threadIdx.x; i < T_ * H_; i += 256) wq_s[i] = Wqt[i];
  const int w = threadIdx.x >> 6, l = threadIdx.x & 63;
  const size_t r = (size_t)blockIdx.x * 4 + w;
  const float4 v = *(const float4*)(hraw + r * H_ + l * 4);
  const float n = fmaxf(sqrtf(wsum(v.x * v.x + v.y * v.y + v.z * v.z + v.w * v.w)), 1e-12f);
  float4 hn; hn.x = v.x / n; hn.y = v.y / n; hn.z = v.z / n; hn.w = v.w / n;
  *(float4*)(h + r * H_ + l * 4) = hn;
  __syncthreads();
  float mine = 0.f;
  for (int tt = 0; tt < T_; tt++) {
    const float4 p4 = *(const float4*)(wq_s + tt * H_ + l * 4);
    float p = hn.x * p4.x + hn.y * p4.y + hn.z * p4.z + hn.w * p4.w;
    p = wsum(p);
    if (l == tt) mine = p + bqt[l];
  }
  float s = (l < T_) ? mine : -1e30f;
  const float m = wmaxr(s);
  const float e = (l < T_) ? expf(s - m) : 0.f;
  const float su = wsum(e);
  if (l < T_) need[r * T_ + l] = e / su;
}

// ---------- step 0: scores, argmax, covered from chosen row ----------
__global__ __launch_bounds__(256)
void score0_kernel(const float* __restrict__ h, const float* __restrict__ se,
                   const float* __restrict__ cn, const float* __restrict__ pro,
                   float* __restrict__ covered, float* __restrict__ chosen,
                   float* __restrict__ logits, float* __restrict__ preds)
{
  __shared__ __align__(16) float hs_s[H_];
  __shared__ __align__(16) float cr_s[H_];
  __shared__ float part_s[T_ * 16];
  __shared__ float sc_s[K_];
  __shared__ float rd_s[4];
  __shared__ int idx_s;
  const int b = blockIdx.x, t = threadIdx.x;
  const int w = t >> 6, l = t & 63;

  const float hv = h[(size_t)b * H_ + t] + se[t];
  const float ss = wsum(hv * hv);
  if (l == 0) rd_s[w] = ss;
  __syncthreads();
  const float n = fmaxf(sqrtf(rd_s[0] + rd_s[1] + rd_s[2] + rd_s[3]), 1e-12f);
  hs_s[t] = hv / n;
  __syncthreads();

  const float4 hf = *(const float4*)(hs_s + l * 4);
#pragma unroll
  for (int cc = 0; cc < 8; cc++) {
    const int c = w * 8 + cc;
    const float4 cv = *(const float4*)(cn + ((size_t)b * K_ + c) * H_ + l * 4);
    float p = wsum(dot4(cv, hf));
    if (l == 0) sc_s[c] = p * 10.f;
  }
  __syncthreads();
  if (w == 0) {
    float s = (l < K_) ? sc_s[l] : -1e30f;
    int bi = (l < K_) ? l : K_;
#pragma unroll
    for (int o = 32; o; o >>= 1) {
      const float s2 = __shfl_xor(s, o);
      const int i2 = __shfl_xor(bi, o);
      if (s2 > s || (s2 == s && i2 < bi)) { s = s2; bi = i2; }
    }
    if (l == 0) idx_s = bi;
  }
  __syncthreads();
  const int idx = idx_s;
  if (t < K_) logits[(size_t)b * (S_ * K_) + t] = sc_s[t];
  if (t == 0) preds[(size_t)b * S_] = (float)idx;

  const float crv = cn[((size_t)b * K_ + idx) * H_ + t];
  cr_s[t] = crv;
  chosen[(size_t)b * H_ + t] = crv;
  __syncthreads();
  {
    const int tt = t & 15, ch = t >> 4;
    float p = 0.f;
#pragma unroll
    for (int j = 0; j < 16; j++)
      p = fmaf(cr_s[ch * 16 + j], pro[tt * H_ + ch * 16 + j], p);
    part_s[tt * 16 + ch] = p;
  }
  __syncthreads();
  if (t < 16) {
    float d = 0.f;
#pragma unroll
    for (int ch = 0; ch < 16; ch++) d += part_s[t * 16 + ch];
    float mx = d;
    mx = fmaxf(mx, __shfl_xor(mx, 1)); mx = fmaxf(mx, __shfl_xor(mx, 2));
    mx = fmaxf(mx, __shfl_xor(mx, 4)); mx = fmaxf(mx, __shfl_xor(mx, 8));
    const float e = expf(d - mx);
    float su = e;
    su += __shfl_xor(su, 1); su += __shfl_xor(su, 2);
    su += __shfl_xor(su, 4); su += __shfl_xor(su, 8);
    covered[(size_t)b * T_ + t] = fminf(e / su, 1.f);
  }
}

// ---------- step 1: GRU + scores + topic gain + argmax ----------
__global__ __launch_bounds__(256)
void score1_kernel(const float* __restrict__ gi, const float* __restrict__ gh,
                   const float* __restrict__ h,  const float* __restrict__ se,
                   const float* __restrict__ cn, const float* __restrict__ pro,
                   const float* __restrict__ need, const float* __restrict__ clam,
                   const float* __restrict__ covered,
                   float* __restrict__ logits, float* __restrict__ preds)
{
  __shared__ __align__(16) float cn_s[K_ * 260];
  __shared__ __align__(16) float pro_s[T_ * 260];
  __shared__ __align__(16) float hs_s[H_];
  __shared__ float gd_s[K_ * T_];
  __shared__ float gain_s[K_];
  __shared__ float nu_s[T_], sc_s[K_], rd_s[4], rd2_s[4];
  const int b = blockIdx.x, t = threadIdx.x;
  const int w = t >> 6, l = t & 63;

  const size_t o = (size_t)b * (3 * H_);
  const float ir = gi[o + t], iz = gi[o + 256 + t], ig = gi[o + 512 + t];
  const float hr = gh[o + t], hz = gh[o + 256 + t], hg = gh[o + 512 + t];
  const float hv = h[(size_t)b * H_ + t];
  const float rr = 1.f / (1.f + expf(-(ir + hr)));
  const float zz = 1.f / (1.f + expf(-(iz + hz)));
  const float nn = tanhf(ig + rr * hg);
  const float x = (1.f - zz) * nn + zz * hv;
  const float ss = wsum(x * x);
  if (l == 0) rd_s[w] = ss;

  {
    const float4* cng = (const float4*)(cn + (size_t)b * K_ * H_);
    float4* cns4 = (float4*)cn_s;
    for (int i = t; i < 2048; i += 256) cns4[(i >> 6) * 65 + (i & 63)] = cng[i];
    const float4* prg = (const float4*)pro;
    float4* prs4 = (float4*)pro_s;
    for (int i = t; i < 1024; i += 256) prs4[(i >> 6) * 65 + (i & 63)] = prg[i];
  }
  if (t < T_)
    nu_s[t] = need[(size_t)b * T_ + t] * fminf(fmaxf(1.f - covered[(size_t)b * T_ + t], 0.f), 1.f);
  __syncthreads();
  const float n1 = fmaxf(sqrtf(rd_s[0] + rd_s[1] + rd_s[2] + rd_s[3]), 1e-12f);
  const float y = x / n1 + se[H_ + t];
  const float ss2 = wsum(y * y);
  if (l == 0) rd2_s[w] = ss2;
  __syncthreads();
  const float n2 = fmaxf(sqrtf(rd2_s[0] + rd2_s[1] + rd2_s[2] + rd2_s[3]), 1e-12f);
  hs_s[t] = y / n2;
  __syncthreads();

  const float4* cn_s4 = (const float4*)cn_s;
  const float4* pro_s4 = (const float4*)pro_s;
  const float4 hf = *(const float4*)(hs_s + l * 4);
#pragma unroll
  for (int cc = 0; cc < 8; cc++) {
    const int c = w * 8 + cc;
    const float4 cv = cn_s4[c * 65 + l];
    float p = wsum(dot4(cv, hf));
    if (l == 0) sc_s[c] = p * 10.f;
  }
#pragma unroll
  for (int pr = 0; pr < 2; pr++) {
    const int idx2 = t + pr * 256;
    const int c = idx2 >> 4, tt = idx2 & 15;
    float d = 0.f;
#pragma unroll 8
    for (int j = 0; j < 64; j++)
      d += dot4(cn_s4[c * 65 + j], pro_s4[tt * 65 + j]);
    gd_s[idx2] = d;
  }
  __syncthreads();
  if (t < K_) {
    float mx = -1e30f;
#pragma unroll
    for (int tt = 0; tt < T_; tt++) mx = fmaxf(mx, gd_s[t * T_ + tt]);
    float su = 0.f, ga = 0.f;
#pragma unroll
    for (int tt = 0; tt < T_; tt++) {
      const float e = expf(gd_s[t * T_ + tt] - mx);
      su += e; ga = fmaf(nu_s[tt], e, ga);
    }
    gain_s[t] = ga / su;
  }
  const int i0 = (int)preds[(size_t)b * S_];
  __syncthreads();
  if (w == 0) {
    const float lam = log1pf(expf(clam[0]));
    float s = (l < K_) ? sc_s[l] + lam * gain_s[l] : -1e30f;
    if (l < K_ && l == i0) s = -100.f;
    if (l < K_) logits[(size_t)b * (S_ * K_) + K_ + l] = s;
    int bi = (l < K_) ? l : K_;
    float sm = s;
#pragma unroll
    for (int o2 = 32; o2; o2 >>= 1) {
      const float s2 = __shfl_xor(sm, o2);
      const int i2 = __shfl_xor(bi, o2);
      if (s2 > sm || (s2 == sm && i2 < bi)) { sm = s2; bi = i2; }
    }
    if (l == 0) preds[(size_t)b * S_ + 1] = (float)bi;
  }
}

extern "C" void kernel_launch(void* const* d_in, const int* in_sizes, int n_in,
                              void* d_out, int out_size, void* d_ws, size_t ws_size,
                              hipStream_t stream)
{
  const float* query_emb = (const float*)d_in[0];
  const float* cand_emb  = (const float*)d_in[1];
  const float* W_in = (const float*)d_in[2];
  const float* Wq_a = (const float*)d_in[3];
  const float* Wk_a = (const float*)d_in[4];
  const float* Wv_a = (const float*)d_in[5];
  const float* bq_a = (const float*)d_in[6];
  const float* bk_a = (const float*)d_in[7];
  const float* bv_a = (const float*)d_in[8];
  const float* Wo_a = (const float*)d_in[9];
  const float* bo_a = (const float*)d_in[10];
  const float* ln_w = (const float*)d_in[11];
  const float* ln_b = (const float*)d_in[12];
  const float* Wq   = (const float*)d_in[13];
  const float* Wc   = (const float*)d_in[14];
  const float* W_ih = (const float*)d_in[15];
  const float* W_hh = (const float*)d_in[16];
  const float* b_ih = (const float*)d_in[17];
  const float* b_hh = (const float*)d_in[18];
  const float* step_emb = (const float*)d_in[19];
  const float* tpro = (const float*)d_in[20];
  const float* Wqt  = (const float*)d_in[21];
  const float* bqt  = (const float*)d_in[22];
  const float* clam = (const float*)d_in[23];

  float* ws = (float*)d_ws;
  size_t o = 0;
  float* WkinT = ws + o; o += (size_t)D_ * H_;
  float* Wv_in = ws + o; o += (size_t)H_ * D_;
  ushort* BhW  = (ushort*)(ws + o); o += 98304;
  ushort* BlW  = (ushort*)(ws + o); o += 98304;
  float* pro   = ws + o; o += (size_t)T_ * H_;
  float* Bqk   = ws + o; o += (size_t)D_ * H_;
  float* bqk   = ws + o; o += 1024;
  float* Wvo   = ws + o; o += (size_t)H_ * D_;
  float* bvo   = ws + o; o += 256;
  float* Wqp   = ws + o; o += (size_t)H_ * H_;
  float* bqp   = ws + o; o += 256;
  float* vqbk  = ws + o; o += 256;
  float* qcst  = ws + o; o += 4;
  ushort* WintH = (ushort*)(ws + o); o += 98304;
  ushort* WintL = (ushort*)(ws + o); o += 98304;
  ushort* BqktH = (ushort*)(ws + o); o += 98304;
  ushort* BqktL = (ushort*)(ws + o); o += 98304;
  ushort* WvotH = (ushort*)(ws + o); o += 98304;
  ushort* WvotL = (ushort*)(ws + o); o += 98304;
  ushort* WqptH = (ushort*)(ws + o); o += 32768;
  ushort* WqptL = (ushort*)(ws + o); o += 32768;
  ushort* WihtH = (ushort*)(ws + o); o += 98304;
  ushort* WihtL = (ushort*)(ws + o); o += 98304;
  ushort* WhhtH = (ushort*)(ws + o); o += 98304;
  ushort* WhhtL = (ushort*)(ws + o); o += 98304;
  float* qr    = ws + o; o += (size_t)B_ * H_;
  float* qkv   = ws + o; o += (size_t)B_ * D_;   // later: gi
  float* wce   = ws + o; o += (size_t)B_ * D_;   // later: gh
  float* ctxb  = ws + o; o += (size_t)B_ * H_;   // hraw
  float* xhat  = ws + o; o += (size_t)B_ * H_;
  float* h     = ws + o; o += (size_t)B_ * H_;
  float* need  = ws + o; o += (size_t)B_ * T_;
  float* cn    = ws + o; o += (size_t)B_ * K_ * H_;
  float* cov   = ws + o; o += (size_t)B_ * T_;
  float* chosen= ws + o; o += (size_t)B_ * H_;

  float* out_logits = (float*)d_out;
  float* out_preds  = (float*)d_out + (size_t)B_ * S_ * K_;

  // weight folding + tiling
  fold_kernel<<<dim3(H_, 3), 256, 0, stream>>>(Wk_a, Wv_a, Wc, W_in, WkinT, Wv_in, BhW, BlW);
  proto_kernel<<<1, 256, 0, stream>>>(tpro, pro);
  fold2_kernel<<<D_, 256, 0, stream>>>(Wq_a, bq_a, bk_a, Wo_a, bo_a, bv_a, Wq, ln_w, ln_b,
                                       WkinT, Wv_in, Bqk, bqk, Wvo, bvo, Wqp, bqp, vqbk, qcst);
  TileJobs jobs;
  jobs.j[0] = {W_in, WintH, WintL, 16, 768, 256};
  jobs.j[1] = {Bqk,  BqktH, BqktL, 48, 256, 768};
  jobs.j[2] = {Wvo,  WvotH, WvotL, 16, 768, 256};
  jobs.j[3] = {Wqp,  WqptH, WqptL, 16, 256, 256};
  jobs.j[4] = {W_ih, WihtH, WihtL, 48, 256, 768};
  jobs.j[5] = {W_hh, WhhtH, WhhtL, 48, 256, 768};
  tile_all<<<dim3(768, 6), 256, 0, stream>>>(jobs);

  // query path
  gemm_bf<24, 16, false><<<dim3(B_ / 128, 4), 256, 0, stream>>>(query_emb, WintH, WintL, nullptr, qr);
  gemm_bf<8, 48, true><<<dim3(B_ / 128, 12), 256, 0, stream>>>(qr, BqktH, BqktL, bqk, qkv);

  // candidate path + fused attention
  gemm_cn_attn<<<(B_ * K_) / 64, 256, 0, stream>>>(cand_emb, BhW, BlW, qkv, qr, vqbk, qcst, cn, wce);

  // ctx gemm + residual + LN fused
  gemm_ctx_ln<<<B_ / 64, 256, 0, stream>>>(wce, WvotH, WvotL, bvo, qr, xhat);
  gemm_bf<8, 16, true><<<dim3(B_ / 128, 4), 256, 0, stream>>>(xhat, WqptH, WqptL, bqp, ctxb);  // hraw
  h_post<<<B_ / 4, 256, 0, stream>>>(ctxb, Wqt, bqt, h, need);

  // step 0 (scores + covered + chosen)
  score0_kernel<<<B_, 256, 0, stream>>>(h, step_emb, cn, pro, cov, chosen, out_logits, out_preds);
  // GRU gates
  gemm_bf<8, 48, true><<<dim3(B_ / 128, 12), 256, 0, stream>>>(chosen, WihtH, WihtL, b_ih, qkv);  // gi
  gemm_bf<8, 48, true><<<dim3(B_ / 128, 12), 256, 0, stream>>>(h, WhhtH, WhhtL, b_hh, wce);       // gh
  // step 1 (GRU + scores + topic gain)
  score1_kernel<<<B_, 256, 0, stream>>>(qkv, wce, h, step_emb, cn, pro, need, clam, cov,
                                        out_logits, out_preds);
}

// Round 12
// 881.627 us; speedup vs baseline: 1.3813x; 1.0030x over previous
//
#include <hip/hip_runtime.h>
#include <math.h>

#define B_ 8192
#define K_ 32
#define D_ 768
#define H_ 256
#define T_ 16
#define S_ 2

typedef unsigned int uint;
typedef unsigned short ushort;
typedef __attribute__((ext_vector_type(8))) short bf16x8;
typedef __attribute__((ext_vector_type(4))) float f32x4;

// ---------- wave (64-lane) reductions ----------
__device__ __forceinline__ float wsum(float v) {
  v += __shfl_xor(v, 32); v += __shfl_xor(v, 16); v += __shfl_xor(v, 8);
  v += __shfl_xor(v, 4);  v += __shfl_xor(v, 2);  v += __shfl_xor(v, 1);
  return v;
}
__device__ __forceinline__ float wmaxr(float v) {
  v = fmaxf(v, __shfl_xor(v, 32)); v = fmaxf(v, __shfl_xor(v, 16));
  v = fmaxf(v, __shfl_xor(v, 8));  v = fmaxf(v, __shfl_xor(v, 4));
  v = fmaxf(v, __shfl_xor(v, 2));  v = fmaxf(v, __shfl_xor(v, 1));
  return v;
}

// barrier that drains ONLY LDS ops (keeps global loads in flight across it)
__device__ __forceinline__ void barrier_lgkm() {
  asm volatile("s_waitcnt lgkmcnt(0)\n\ts_barrier" ::: "memory");
}

// split fp32 -> (hi bf16 trunc, lo bf16 trunc of exact remainder), packed 2/uint
__device__ __forceinline__ void split4(const float4 f, uint2& h, uint2& lo) {
  const uint ux = __float_as_uint(f.x), uy = __float_as_uint(f.y);
  const uint uz = __float_as_uint(f.z), uw = __float_as_uint(f.w);
  h.x = (uy & 0xFFFF0000u) | (ux >> 16);
  h.y = (uw & 0xFFFF0000u) | (uz >> 16);
  const float rx = f.x - __uint_as_float(ux & 0xFFFF0000u);
  const float ry = f.y - __uint_as_float(uy & 0xFFFF0000u);
  const float rz = f.z - __uint_as_float(uz & 0xFFFF0000u);
  const float rw = f.w - __uint_as_float(uw & 0xFFFF0000u);
  lo.x = (__float_as_uint(ry) & 0xFFFF0000u) | (__float_as_uint(rx) >> 16);
  lo.y = (__float_as_uint(rw) & 0xFFFF0000u) | (__float_as_uint(rz) >> 16);
}

__device__ __forceinline__ float dot4(const float4 a, const float4 b) {
  float s = a.x * b.x;
  s = fmaf(a.y, b.y, s); s = fmaf(a.z, b.z, s); s = fmaf(a.w, b.w, s);
  return s;
}

// B frag tiling (NB = N/16): elem(n,k) -> ((ks*NB + nb)*64 + (nl | kc<<4))*8 + kb

// ---------- fold stage 1: WkinT fp32, Wv_in fp32, Wc_in -> hi/lo bf16 frag-tiled (NB=16) ----------
__global__ __launch_bounds__(256)
void fold_kernel(const float* __restrict__ Wk_a, const float* __restrict__ Wv_a,
                 const float* __restrict__ Wc,  const float* __restrict__ W_in,
                 float* __restrict__ WkinT, float* __restrict__ Wv_in,
                 ushort* __restrict__ Bh, ushort* __restrict__ Bl)
{
  const int i = blockIdx.x;
  const int m = blockIdx.y;
  const float* Wx = (m == 0) ? Wk_a : ((m == 1) ? Wv_a : Wc);
  const int t = threadIdx.x;
  float a0 = 0.f, a1 = 0.f, a2 = 0.f;
  for (int k = 0; k < H_; k++) {
    const float wv = Wx[i * H_ + k];
    const float* row = W_in + (size_t)k * D_;
    a0 = fmaf(wv, row[t], a0);
    a1 = fmaf(wv, row[t + 256], a1);
    a2 = fmaf(wv, row[t + 512], a2);
  }
  if (m == 0) {
    WkinT[(size_t)t * H_ + i] = a0;
    WkinT[(size_t)(t + 256) * H_ + i] = a1;
    WkinT[(size_t)(t + 512) * H_ + i] = a2;
  } else if (m == 1) {
    float* o = Wv_in + (size_t)i * D_;
    o[t] = a0; o[t + 256] = a1; o[t + 512] = a2;
  } else {
    const float vals[3] = {a0, a1, a2};
#pragma unroll
    for (int j = 0; j < 3; j++) {
      const int k = t + j * 256;
      const float v = vals[j];
      const int idx = (((k >> 5) * 16 + (i >> 4)) * 64 + ((i & 15) | (((k >> 3) & 3) << 4))) * 8 + (k & 7);
      const uint u = __float_as_uint(v);
      Bh[idx] = (ushort)(u >> 16);
      const float rr = v - __uint_as_float(u & 0xFFFF0000u);
      Bl[idx] = (ushort)(__float_as_uint(rr) >> 16);
    }
  }
}

// ---------- all weight tilings in one launch ----------
struct TileJob { const float* W; ushort* Bh; ushort* Bl; int NB; int K; int rows; };
struct TileJobs { TileJob j[6]; };

__global__ __launch_bounds__(256)
void tile_all(TileJobs jobs)
{
  const TileJob J = jobs.j[blockIdx.y];
  const int n = blockIdx.x;
  if (n >= J.rows) return;
  const int t = threadIdx.x;
  for (int k = t; k < J.K; k += 256) {
    const float v = J.W[(size_t)n * J.K + k];
    const int idx = (((k >> 5) * J.NB + (n >> 4)) * 64 + ((n & 15) | (((k >> 3) & 3) << 4))) * 8 + (k & 7);
    const uint u = __float_as_uint(v);
    J.Bh[idx] = (ushort)(u >> 16);
    const float rr = v - __uint_as_float(u & 0xFFFF0000u);
    J.Bl[idx] = (ushort)(__float_as_uint(rr) >> 16);
  }
}

// ---------- l2-normalize topic prototypes ----------
__global__ __launch_bounds__(256)
void proto_kernel(const float* __restrict__ tpro, float* __restrict__ pro)
{
  const int w = threadIdx.x >> 6, l = threadIdx.x & 63;
  for (int r = w; r < T_; r += 4) {
    const float4 v = *(const float4*)(tpro + (size_t)r * H_ + l * 4);
    const float n = fmaxf(sqrtf(wsum(v.x * v.x + v.y * v.y + v.z * v.z + v.w * v.w)), 1e-12f);
    float4 o; o.x = v.x / n; o.y = v.y / n; o.z = v.z / n; o.w = v.w / n;
    *(float4*)(pro + (size_t)r * H_ + l * 4) = o;
  }
}

// ---------- fold stage 2: attention/query-path weight folds ----------
__global__ __launch_bounds__(256)
void fold2_kernel(const float* __restrict__ Wq_a, const float* __restrict__ bq_a,
                  const float* __restrict__ bk_a, const float* __restrict__ Wo_a,
                  const float* __restrict__ bo_a, const float* __restrict__ bv_a,
                  const float* __restrict__ Wq,   const float* __restrict__ ln_w,
                  const float* __restrict__ ln_b, const float* __restrict__ WkinT,
                  const float* __restrict__ Wv_in,
                  float* __restrict__ Bqk, float* __restrict__ bqk,
                  float* __restrict__ Wvo, float* __restrict__ bvo,
                  float* __restrict__ Wqp, float* __restrict__ bqp,
                  float* __restrict__ vqbk, float* __restrict__ qcst)
{
  __shared__ float rd_s[4];
  const int n = blockIdx.x, t = threadIdx.x, w = t >> 6, l = t & 63;
  float s = 0.f;
  for (int hh = 0; hh < H_; hh++)
    s = fmaf(Wq_a[hh * H_ + t], WkinT[(size_t)n * H_ + hh], s);
  Bqk[(size_t)n * H_ + t] = s;
  float p = bq_a[t] * WkinT[(size_t)n * H_ + t];
  p = wsum(p);
  if (l == 0) rd_s[w] = p;
  __syncthreads();
  if (t == 0) bqk[n] = rd_s[0] + rd_s[1] + rd_s[2] + rd_s[3];
  if (n < H_) {
    float a0 = 0.f, a1 = 0.f, a2 = 0.f;
    for (int hh = 0; hh < H_; hh++) {
      const float wo = Wo_a[n * H_ + hh];
      const float* rowv = Wv_in + (size_t)hh * D_;
      a0 = fmaf(wo, rowv[t], a0);
      a1 = fmaf(wo, rowv[t + 256], a1);
      a2 = fmaf(wo, rowv[t + 512], a2);
    }
    Wvo[(size_t)n * D_ + t] = a0;
    Wvo[(size_t)n * D_ + t + 256] = a1;
    Wvo[(size_t)n * D_ + t + 512] = a2;
    float pb = Wo_a[n * H_ + t] * bv_a[t];
    pb = wsum(pb);
    __syncthreads();
    if (l == 0) rd_s[w] = pb;
    __syncthreads();
    if (t == 0) bvo[n] = rd_s[0] + rd_s[1] + rd_s[2] + rd_s[3] + bo_a[n];
    Wqp[n * H_ + t] = Wq[n * H_ + t] * ln_w[t];
    float pq = Wq[n * H_ + t] * ln_b[t];
    pq = wsum(pq);
    __syncthreads();
    if (l == 0) rd_s[w] = pq;
    __syncthreads();
    if (t == 0) bqp[n] = rd_s[0] + rd_s[1] + rd_s[2] + rd_s[3];
  }
  if (n == 0) {
    float sv = 0.f;
    for (int hh = 0; hh < H_; hh++) sv = fmaf(bk_a[hh], Wq_a[hh * H_ + t], sv);
    vqbk[t] = sv;
    float pc = bq_a[t] * bk_a[t];
    pc = wsum(pc);
    __syncthreads();
    if (l == 0) rd_s[w] = pc;
    __syncthreads();
    if (t == 0) qcst[0] = rd_s[0] + rd_s[1] + rd_s[2] + rd_s[3];
  }
}

// ---------- fused gemm_cn + cross-attention (LDS A-dbuf, lgkm-only loop barriers) ----------
__global__ __launch_bounds__(256, 3)
void gemm_cn_attn(const float* __restrict__ A, const ushort* __restrict__ Bh,
                  const ushort* __restrict__ Bl, const float* __restrict__ qkv,
                  const float* __restrict__ qr, const float* __restrict__ vqbk,
                  const float* __restrict__ qcst, float* __restrict__ C,
                  float* __restrict__ wce)
{
  __shared__ __align__(16) ushort AhS[2][2048], AlS[2][2048];
  __shared__ __align__(16) float4 qkv_s[384];
  __shared__ float sc_s[64], at_s[64], qbk_s[2];
  __shared__ float rsq[64][4];
  const int t = threadIdx.x, l = t & 63, w = t >> 6;
  const int r = t >> 2, kc = t & 3;
  const int tb = t >> 7;
  const float* Ag = A + ((size_t)blockIdx.x * 64 + r) * 768 + kc * 8;
  const int aslot = ((r >> 4) * 64 + ((r & 15) | (kc << 4))) * 8;
  const ushort* Bhb = Bh + ((w * 4) * 64 + l) * 8;
  const ushort* Blb = Bl + ((w * 4) * 64 + l) * 8;

  for (int i = t; i < 384; i += 256)
    qkv_s[i] = ((const float4*)qkv)[(size_t)blockIdx.x * 384 + i];
  if (w < 2) {
    const float4 q4 = ((const float4*)qr)[((size_t)blockIdx.x * 2 + w) * 64 + l];
    const float4 v4 = ((const float4*)vqbk)[l];
    float p = wsum(dot4(q4, v4));
    if (l == 0) qbk_s[w] = p + qcst[0];
  }

  f32x4 acc[4][4];
#pragma unroll
  for (int i = 0; i < 4; i++)
#pragma unroll
    for (int j = 0; j < 4; j++) acc[i][j] = (f32x4)0.f;

  float sc = 0.f;
  float4 f0 = *(const float4*)(Ag);
  float4 f1 = *(const float4*)(Ag + 4);
  __syncthreads();  // qkv_s ready
  sc += dot4(f0, qkv_s[tb * 192 + kc * 2]) + dot4(f1, qkv_s[tb * 192 + kc * 2 + 1]);
  {
    uint2 ha, la, hb, lb;
    split4(f0, ha, la); split4(f1, hb, lb);
    *(uint4*)&AhS[0][aslot] = make_uint4(ha.x, ha.y, hb.x, hb.y);
    *(uint4*)&AlS[0][aslot] = make_uint4(la.x, la.y, lb.x, lb.y);
  }
  f0 = *(const float4*)(Ag + 32);
  f1 = *(const float4*)(Ag + 36);
  barrier_lgkm();

#pragma unroll 2
  for (int ks = 0; ks < 24; ks++) {
    const int cur = ks & 1;
    uint4 bhv[4], blv[4];
#pragma unroll
    for (int ni = 0; ni < 4; ni++) {
      bhv[ni] = *(const uint4*)(Bhb + ks * 8192 + ni * 512);
      blv[ni] = *(const uint4*)(Blb + ks * 8192 + ni * 512);
    }
    if (ks < 23) {
      sc += dot4(f0, qkv_s[tb * 192 + (ks + 1) * 8 + kc * 2]) +
            dot4(f1, qkv_s[tb * 192 + (ks + 1) * 8 + kc * 2 + 1]);
      uint2 ha, la, hb, lb;
      split4(f0, ha, la); split4(f1, hb, lb);
      *(uint4*)&AhS[cur ^ 1][aslot] = make_uint4(ha.x, ha.y, hb.x, hb.y);
      *(uint4*)&AlS[cur ^ 1][aslot] = make_uint4(la.x, la.y, lb.x, lb.y);
      if (ks < 22) {
        f0 = *(const float4*)(Ag + (ks + 2) * 32);
        f1 = *(const float4*)(Ag + (ks + 2) * 32 + 4);
      }
    }
#pragma unroll
    for (int mi = 0; mi < 4; mi++) {
      const bf16x8 ah = *(const bf16x8*)&AhS[cur][(mi * 64 + l) * 8];
      const bf16x8 al = *(const bf16x8*)&AlS[cur][(mi * 64 + l) * 8];
#pragma unroll
      for (int ni = 0; ni < 4; ni++) {
        const bf16x8 bhf = *(const bf16x8*)&bhv[ni];
        const bf16x8 blf = *(const bf16x8*)&blv[ni];
        acc[mi][ni] = __builtin_amdgcn_mfma_f32_16x16x32_bf16(ah, bhf, acc[mi][ni], 0, 0, 0);
        acc[mi][ni] = __builtin_amdgcn_mfma_f32_16x16x32_bf16(al, bhf, acc[mi][ni], 0, 0, 0);
        acc[mi][ni] = __builtin_amdgcn_mfma_f32_16x16x32_bf16(ah, blf, acc[mi][ni], 0, 0, 0);
      }
    }
    barrier_lgkm();  // LDS ordering only; global loads stay in flight
  }

  sc += __shfl_xor(sc, 1);
  sc += __shfl_xor(sc, 2);
  if ((t & 3) == 0) sc_s[r] = sc;
  __syncthreads();
  if (w < 2) {
    float s = (l < 32) ? (sc_s[w * 32 + l] + qbk_s[w]) * (1.f / 16.f) : -1e30f;
    const float m = wmaxr(s);
    const float e = (l < 32) ? expf(s - m) : 0.f;
    const float su = wsum(e);
    if (l < 32) at_s[w * 32 + l] = e / su;
  }
  __syncthreads();
#pragma unroll
  for (int p = 0; p < 2; p++) {
    const int slot = t + p * 256;
    if (slot < 384) {
      const int tb2 = slot >= 192;
      const int idx = slot - tb2 * 192;
      const float4* cb = (const float4*)A + ((size_t)blockIdx.x * 64 + tb2 * 32) * 192 + idx;
      float4 a = make_float4(0.f, 0.f, 0.f, 0.f);
#pragma unroll 4
      for (int c = 0; c < 32; c++) {
        const float av = at_s[tb2 * 32 + c];
        const float4 f = cb[c * 192];
        a.x = fmaf(av, f.x, a.x); a.y = fmaf(av, f.y, a.y);
        a.z = fmaf(av, f.z, a.z); a.w = fmaf(av, f.w, a.w);
      }
      ((float4*)wce)[((size_t)blockIdx.x * 2 + tb2) * 192 + idx] = a;
    }
  }

#pragma unroll
  for (int mi = 0; mi < 4; mi++)
#pragma unroll
    for (int rg = 0; rg < 4; rg++) {
      float p = 0.f;
#pragma unroll
      for (int ni = 0; ni < 4; ni++) { const float v = acc[mi][ni][rg]; p = fmaf(v, v, p); }
      p += __shfl_xor(p, 1); p += __shfl_xor(p, 2); p += __shfl_xor(p, 4); p += __shfl_xor(p, 8);
      if ((l & 15) == 0) rsq[mi * 16 + (l >> 4) * 4 + rg][w] = p;
    }
  __syncthreads();
  const size_t row0 = (size_t)blockIdx.x * 64;
#pragma unroll
  for (int mi = 0; mi < 4; mi++)
#pragma unroll
    for (int rg = 0; rg < 4; rg++) {
      const int rl = mi * 16 + (l >> 4) * 4 + rg;
      const float ssum = rsq[rl][0] + rsq[rl][1] + rsq[rl][2] + rsq[rl][3];
      const float inv = 1.f / fmaxf(sqrtf(ssum), 1e-12f);
#pragma unroll
      for (int ni = 0; ni < 4; ni++)
        C[(row0 + rl) * H_ + w * 64 + ni * 16 + (l & 15)] = acc[mi][ni][rg] * inv;
    }
}

// ---------- gemm ctx + residual + LayerNorm fused: xhat = LN(wce@Wvo^T + bvo + qr) ----------
__global__ __launch_bounds__(256, 3)
void gemm_ctx_ln(const float* __restrict__ A, const ushort* __restrict__ Bh,
                 const ushort* __restrict__ Bl, const float* __restrict__ bvo,
                 const float* __restrict__ qr, float* __restrict__ xhat)
{
  __shared__ __align__(16) ushort AhS[2][2048], AlS[2][2048];
  __shared__ float red[64][4][2];
  const int t = threadIdx.x, l = t & 63, w = t >> 6;
  const int r = t >> 2, kc = t & 3;
  const float* Ag = A + ((size_t)blockIdx.x * 64 + r) * 768 + kc * 8;
  const int aslot = ((r >> 4) * 64 + ((r & 15) | (kc << 4))) * 8;
  const ushort* Bhb = Bh + ((w * 4) * 64 + l) * 8;
  const ushort* Blb = Bl + ((w * 4) * 64 + l) * 8;

  f32x4 acc[4][4];
#pragma unroll
  for (int i = 0; i < 4; i++)
#pragma unroll
    for (int j = 0; j < 4; j++) acc[i][j] = (f32x4)0.f;

  float4 f0 = *(const float4*)(Ag);
  float4 f1 = *(const float4*)(Ag + 4);
  {
    uint2 ha, la, hb, lb;
    split4(f0, ha, la); split4(f1, hb, lb);
    *(uint4*)&AhS[0][aslot] = make_uint4(ha.x, ha.y, hb.x, hb.y);
    *(uint4*)&AlS[0][aslot] = make_uint4(la.x, la.y, lb.x, lb.y);
  }
  f0 = *(const float4*)(Ag + 32);
  f1 = *(const float4*)(Ag + 36);
  barrier_lgkm();

#pragma unroll 2
  for (int ks = 0; ks < 24; ks++) {
    const int cur = ks & 1;
    uint4 bhv[4], blv[4];
#pragma unroll
    for (int ni = 0; ni < 4; ni++) {
      bhv[ni] = *(const uint4*)(Bhb + ks * 8192 + ni * 512);
      blv[ni] = *(const uint4*)(Blb + ks * 8192 + ni * 512);
    }
    if (ks < 23) {
      uint2 ha, la, hb, lb;
      split4(f0, ha, la); split4(f1, hb, lb);
      *(uint4*)&AhS[cur ^ 1][aslot] = make_uint4(ha.x, ha.y, hb.x, hb.y);
      *(uint4*)&AlS[cur ^ 1][aslot] = make_uint4(la.x, la.y, lb.x, lb.y);
      if (ks < 22) {
        f0 = *(const float4*)(Ag + (ks + 2) * 32);
        f1 = *(const float4*)(Ag + (ks + 2) * 32 + 4);
      }
    }
#pragma unroll
    for (int mi = 0; mi < 4; mi++) {
      const bf16x8 ah = *(const bf16x8*)&AhS[cur][(mi * 64 + l) * 8];
      const bf16x8 al = *(const bf16x8*)&AlS[cur][(mi * 64 + l) * 8];
#pragma unroll
      for (int ni = 0; ni < 4; ni++) {
        const bf16x8 bhf = *(const bf16x8*)&bhv[ni];
        const bf16x8 blf = *(const bf16x8*)&blv[ni];
        acc[mi][ni] = __builtin_amdgcn_mfma_f32_16x16x32_bf16(ah, bhf, acc[mi][ni], 0, 0, 0);
        acc[mi][ni] = __builtin_amdgcn_mfma_f32_16x16x32_bf16(al, bhf, acc[mi][ni], 0, 0, 0);
        acc[mi][ni] = __builtin_amdgcn_mfma_f32_16x16x32_bf16(ah, blf, acc[mi][ni], 0, 0, 0);
      }
    }
    barrier_lgkm();
  }

  const size_t row0 = (size_t)blockIdx.x * 64;
#pragma unroll
  for (int mi = 0; mi < 4; mi++)
#pragma unroll
    for (int rg = 0; rg < 4; rg++) {
      const int rl = mi * 16 + (l >> 4) * 4 + rg;
      float sx = 0.f, sxx = 0.f;
#pragma unroll
      for (int ni = 0; ni < 4; ni++) {
        const int col = w * 64 + ni * 16 + (l & 15);
        const float x = acc[mi][ni][rg] + bvo[col] + qr[(row0 + rl) * H_ + col];
        acc[mi][ni][rg] = x;
        sx += x; sxx = fmaf(x, x, sxx);
      }
      sx += __shfl_xor(sx, 1); sx += __shfl_xor(sx, 2); sx += __shfl_xor(sx, 4); sx += __shfl_xor(sx, 8);
      sxx += __shfl_xor(sxx, 1); sxx += __shfl_xor(sxx, 2); sxx += __shfl_xor(sxx, 4); sxx += __shfl_xor(sxx, 8);
      if ((l & 15) == 0) { red[rl][w][0] = sx; red[rl][w][1] = sxx; }
    }
  __syncthreads();
#pragma unroll
  for (int mi = 0; mi < 4; mi++)
#pragma unroll
    for (int rg = 0; rg < 4; rg++) {
      const int rl = mi * 16 + (l >> 4) * 4 + rg;
      const float SX = red[rl][0][0] + red[rl][1][0] + red[rl][2][0] + red[rl][3][0];
      const float SXX = red[rl][0][1] + red[rl][1][1] + red[rl][2][1] + red[rl][3][1];
      const float mu = SX * (1.f / H_);
      const float var = SXX * (1.f / H_) - mu * mu;
      const float isd = 1.f / sqrtf(var + 1e-5f);
#pragma unroll
      for (int ni = 0; ni < 4; ni++)
        xhat[(row0 + rl) * H_ + w * 64 + ni * 16 + (l & 15)] = (acc[mi][ni][rg] - mu) * isd;
    }
}

// ---------- generic split-bf16 MFMA GEMM: C[M,N] = A[M,K]*B^T (+bias), B pre-tiled ----------
template<int NKS, int NB, bool BIAS>
__global__ __launch_bounds__(256)
void gemm_bf(const float* __restrict__ A, const ushort* __restrict__ Bh,
             const ushort* __restrict__ Bl, const float* __restrict__ bias,
             float* __restrict__ C)
{
  __shared__ __align__(16) ushort AhS[2][4096], AlS[2][4096];
  const int t = threadIdx.x, l = t & 63, w = t >> 6;
  const int wr = w >> 1, wc = w & 1;
  const int Kd = NKS * 32, N = NB * 16;
  const int r = t >> 1, kc0 = (t & 1) * 2;
  const float* Ag = A + ((size_t)blockIdx.x * 128 + r) * Kd + kc0 * 8;
  const int aslot0 = ((r >> 4) * 64 + ((r & 15) | (kc0 << 4))) * 8;
  const int aslot1 = aslot0 + 128;
  const int nb0 = blockIdx.y * 4 + wc * 2;
  const ushort* Bhb = Bh + (nb0 * 64 + l) * 8;
  const ushort* Blb = Bl + (nb0 * 64 + l) * 8;

  f32x4 acc[4][2];
#pragma unroll
  for (int i = 0; i < 4; i++)
#pragma unroll
    for (int j = 0; j < 2; j++) acc[i][j] = (f32x4)0.f;

  float4 f0 = *(const float4*)(Ag);
  float4 f1 = *(const float4*)(Ag + 4);
  float4 f2 = *(const float4*)(Ag + 8);
  float4 f3 = *(const float4*)(Ag + 12);
  {
    uint2 ha, la, hb, lb;
    split4(f0, ha, la); split4(f1, hb, lb);
    *(uint4*)&AhS[0][aslot0] = make_uint4(ha.x, ha.y, hb.x, hb.y);
    *(uint4*)&AlS[0][aslot0] = make_uint4(la.x, la.y, lb.x, lb.y);
    split4(f2, ha, la); split4(f3, hb, lb);
    *(uint4*)&AhS[0][aslot1] = make_uint4(ha.x, ha.y, hb.x, hb.y);
    *(uint4*)&AlS[0][aslot1] = make_uint4(la.x, la.y, lb.x, lb.y);
  }
  f0 = *(const float4*)(Ag + 32); f1 = *(const float4*)(Ag + 36);
  f2 = *(const float4*)(Ag + 40); f3 = *(const float4*)(Ag + 44);
  barrier_lgkm();

#pragma unroll 2
  for (int ks = 0; ks < NKS; ks++) {
    const int cur = ks & 1;
    if (ks < NKS - 1) {
      uint2 ha, la, hb, lb;
      split4(f0, ha, la); split4(f1, hb, lb);
      *(uint4*)&AhS[cur ^ 1][aslot0] = make_uint4(ha.x, ha.y, hb.x, hb.y);
      *(uint4*)&AlS[cur ^ 1][aslot0] = make_uint4(la.x, la.y, lb.x, lb.y);
      split4(f2, ha, la); split4(f3, hb, lb);
      *(uint4*)&AhS[cur ^ 1][aslot1] = make_uint4(ha.x, ha.y, hb.x, hb.y);
      *(uint4*)&AlS[cur ^ 1][aslot1] = make_uint4(la.x, la.y, lb.x, lb.y);
      if (ks < NKS - 2) {
        f0 = *(const float4*)(Ag + (ks + 2) * 32);
        f1 = *(const float4*)(Ag + (ks + 2) * 32 + 4);
        f2 = *(const float4*)(Ag + (ks + 2) * 32 + 8);
        f3 = *(const float4*)(Ag + (ks + 2) * 32 + 12);
      }
    }
#pragma unroll
    for (int mi = 0; mi < 4; mi++) {
      const bf16x8 ah = *(const bf16x8*)&AhS[cur][((wr * 4 + mi) * 64 + l) * 8];
      const bf16x8 al = *(const bf16x8*)&AlS[cur][((wr * 4 + mi) * 64 + l) * 8];
#pragma unroll
      for (int ni = 0; ni < 2; ni++) {
        const bf16x8 bhf = *(const bf16x8*)(Bhb + ks * (NB * 512) + ni * 512);
        const bf16x8 blf = *(const bf16x8*)(Blb + ks * (NB * 512) + ni * 512);
        acc[mi][ni] = __builtin_amdgcn_mfma_f32_16x16x32_bf16(ah, bhf, acc[mi][ni], 0, 0, 0);
        acc[mi][ni] = __builtin_amdgcn_mfma_f32_16x16x32_bf16(al, bhf, acc[mi][ni], 0, 0, 0);
        acc[mi][ni] = __builtin_amdgcn_mfma_f32_16x16x32_bf16(ah, blf, acc[mi][ni], 0, 0, 0);
      }
    }
    barrier_lgkm();
  }

  const size_t row0 = (size_t)blockIdx.x * 128 + wr * 64;
  const int col0 = blockIdx.y * 64 + wc * 32;
#pragma unroll
  for (int mi = 0; mi < 4; mi++)
#pragma unroll
    for (int ni = 0; ni < 2; ni++) {
      const int col = col0 + ni * 16 + (l & 15);
      const float bb = BIAS ? bias[col] : 0.f;
#pragma unroll
      for (int rg = 0; rg < 4; rg++) {
        const size_t row = row0 + mi * 16 + (l >> 4) * 4 + rg;
        C[row * N + col] = acc[mi][ni][rg] + bb;
      }
    }
}

// ---------- h = l2n(hraw); need = softmax(h@Wqt^T + bqt) ----------
__global__ __launch_bounds__(256)
void h_post(const float* __restrict__ hraw, const float* __restrict__ Wqt,
            const float* __restrict__ bqt, float* __restrict__ h, float* __restrict__ need)
{
  __shared__ float wq_s[T_ * H_];
  for (int i = threadIdx.x; i < T_ * H_; i += 256) wq_s[i] = Wqt[i];
  const int w = threadIdx.x >> 6, l = threadIdx.x & 63;
  const size_t r = (size_t)blockIdx.x * 4 + w;
  const float4 v = *(const float4*)(hraw + r * H_ + l * 4);
  const float n = fmaxf(sqrtf(wsum(v.x * v.x + v.y * v.y + v.z * v.z + v.w * v.w)), 1e-12f);
  float4 hn; hn.x = v.x / n; hn.y = v.y / n; hn.z = v.z / n; hn.w = v.w / n;
  *(float4*)(h + r * H_ + l * 4) = hn;
  __syncthreads();
  float mine = 0.f;
  for (int tt = 0; tt < T_; tt++) {
    const float4 p4 = *(const float4*)(wq_s + tt * H_ + l * 4);
    float p = hn.x * p4.x + hn.y * p4.y + hn.z * p4.z + hn.w * p4.w;
    p = wsum(p);
    if (l == tt) mine = p + bqt[l];
  }
  float s = (l < T_) ? mine : -1e30f;
  const float m = wmaxr(s);
  const float e = (l < T_) ? expf(s - m) : 0.f;
  const float su = wsum(e);
  if (l < T_) need[r * T_ + l] = e / su;
}

// ---------- step 0: scores, argmax, covered from chosen row ----------
__global__ __launch_bounds__(256)
void score0_kernel(const float* __restrict__ h, const float* __restrict__ se,
                   const float* __restrict__ cn, const float* __restrict__ pro,
                   float* __restrict__ covered, float* __restrict__ chosen,
                   float* __restrict__ logits, float* __restrict__ preds)
{
  __shared__ __align__(16) float hs_s[H_];
  __shared__ __align__(16) float cr_s[H_];
  __shared__ float part_s[T_ * 16];
  __shared__ float sc_s[K_];
  __shared__ float rd_s[4];
  __shared__ int idx_s;
  const int b = blockIdx.x, t = threadIdx.x;
  const int w = t >> 6, l = t & 63;

  const float hv = h[(size_t)b * H_ + t] + se[t];
  const float ss = wsum(hv * hv);
  if (l == 0) rd_s[w] = ss;
  __syncthreads();
  const float n = fmaxf(sqrtf(rd_s[0] + rd_s[1] + rd_s[2] + rd_s[3]), 1e-12f);
  hs_s[t] = hv / n;
  __syncthreads();

  const float4 hf = *(const float4*)(hs_s + l * 4);
#pragma unroll
  for (int cc = 0; cc < 8; cc++) {
    const int c = w * 8 + cc;
    const float4 cv = *(const float4*)(cn + ((size_t)b * K_ + c) * H_ + l * 4);
    float p = wsum(dot4(cv, hf));
    if (l == 0) sc_s[c] = p * 10.f;
  }
  __syncthreads();
  if (w == 0) {
    float s = (l < K_) ? sc_s[l] : -1e30f;
    int bi = (l < K_) ? l : K_;
#pragma unroll
    for (int o = 32; o; o >>= 1) {
      const float s2 = __shfl_xor(s, o);
      const int i2 = __shfl_xor(bi, o);
      if (s2 > s || (s2 == s && i2 < bi)) { s = s2; bi = i2; }
    }
    if (l == 0) idx_s = bi;
  }
  __syncthreads();
  const int idx = idx_s;
  if (t < K_) logits[(size_t)b * (S_ * K_) + t] = sc_s[t];
  if (t == 0) preds[(size_t)b * S_] = (float)idx;

  const float crv = cn[((size_t)b * K_ + idx) * H_ + t];
  cr_s[t] = crv;
  chosen[(size_t)b * H_ + t] = crv;
  __syncthreads();
  {
    const int tt = t & 15, ch = t >> 4;
    float p = 0.f;
#pragma unroll
    for (int j = 0; j < 16; j++)
      p = fmaf(cr_s[ch * 16 + j], pro[tt * H_ + ch * 16 + j], p);
    part_s[tt * 16 + ch] = p;
  }
  __syncthreads();
  if (t < 16) {
    float d = 0.f;
#pragma unroll
    for (int ch = 0; ch < 16; ch++) d += part_s[t * 16 + ch];
    float mx = d;
    mx = fmaxf(mx, __shfl_xor(mx, 1)); mx = fmaxf(mx, __shfl_xor(mx, 2));
    mx = fmaxf(mx, __shfl_xor(mx, 4)); mx = fmaxf(mx, __shfl_xor(mx, 8));
    const float e = expf(d - mx);
    float su = e;
    su += __shfl_xor(su, 1); su += __shfl_xor(su, 2);
    su += __shfl_xor(su, 4); su += __shfl_xor(su, 8);
    covered[(size_t)b * T_ + t] = fminf(e / su, 1.f);
  }
}

// ---------- step 1: GRU + scores + topic gain + argmax ----------
__global__ __launch_bounds__(256)
void score1_kernel(const float* __restrict__ gi, const float* __restrict__ gh,
                   const float* __restrict__ h,  const float* __restrict__ se,
                   const float* __restrict__ cn, const float* __restrict__ pro,
                   const float* __restrict__ need, const float* __restrict__ clam,
                   const float* __restrict__ covered,
                   float* __restrict__ logits, float* __restrict__ preds)
{
  __shared__ __align__(16) float cn_s[K_ * 260];
  __shared__ __align__(16) float pro_s[T_ * 260];
  __shared__ __align__(16) float hs_s[H_];
  __shared__ float gd_s[K_ * T_];
  __shared__ float gain_s[K_];
  __shared__ float nu_s[T_], sc_s[K_], rd_s[4], rd2_s[4];
  const int b = blockIdx.x, t = threadIdx.x;
  const int w = t >> 6, l = t & 63;

  const size_t o = (size_t)b * (3 * H_);
  const float ir = gi[o + t], iz = gi[o + 256 + t], ig = gi[o + 512 + t];
  const float hr = gh[o + t], hz = gh[o + 256 + t], hg = gh[o + 512 + t];
  const float hv = h[(size_t)b * H_ + t];
  const float rr = 1.f / (1.f + expf(-(ir + hr)));
  const float zz = 1.f / (1.f + expf(-(iz + hz)));
  const float nn = tanhf(ig + rr * hg);
  const float x = (1.f - zz) * nn + zz * hv;
  const float ss = wsum(x * x);
  if (l == 0) rd_s[w] = ss;

  {
    const float4* cng = (const float4*)(cn + (size_t)b * K_ * H_);
    float4* cns4 = (float4*)cn_s;
    for (int i = t; i < 2048; i += 256) cns4[(i >> 6) * 65 + (i & 63)] = cng[i];
    const float4* prg = (const float4*)pro;
    float4* prs4 = (float4*)pro_s;
    for (int i = t; i < 1024; i += 256) prs4[(i >> 6) * 65 + (i & 63)] = prg[i];
  }
  if (t < T_)
    nu_s[t] = need[(size_t)b * T_ + t] * fminf(fmaxf(1.f - covered[(size_t)b * T_ + t], 0.f), 1.f);
  __syncthreads();
  const float n1 = fmaxf(sqrtf(rd_s[0] + rd_s[1] + rd_s[2] + rd_s[3]), 1e-12f);
  const float y = x / n1 + se[H_ + t];
  const float ss2 = wsum(y * y);
  if (l == 0) rd2_s[w] = ss2;
  __syncthreads();
  const float n2 = fmaxf(sqrtf(rd2_s[0] + rd2_s[1] + rd2_s[2] + rd2_s[3]), 1e-12f);
  hs_s[t] = y / n2;
  __syncthreads();

  const float4* cn_s4 = (const float4*)cn_s;
  const float4* pro_s4 = (const float4*)pro_s;
  const float4 hf = *(const float4*)(hs_s + l * 4);
#pragma unroll
  for (int cc = 0; cc < 8; cc++) {
    const int c = w * 8 + cc;
    const float4 cv = cn_s4[c * 65 + l];
    float p = wsum(dot4(cv, hf));
    if (l == 0) sc_s[c] = p * 10.f;
  }
#pragma unroll
  for (int pr = 0; pr < 2; pr++) {
    const int idx2 = t + pr * 256;
    const int c = idx2 >> 4, tt = idx2 & 15;
    float d = 0.f;
#pragma unroll 8
    for (int j = 0; j < 64; j++)
      d += dot4(cn_s4[c * 65 + j], pro_s4[tt * 65 + j]);
    gd_s[idx2] = d;
  }
  __syncthreads();
  if (t < K_) {
    float mx = -1e30f;
#pragma unroll
    for (int tt = 0; tt < T_; tt++) mx = fmaxf(mx, gd_s[t * T_ + tt]);
    float su = 0.f, ga = 0.f;
#pragma unroll
    for (int tt = 0; tt < T_; tt++) {
      const float e = expf(gd_s[t * T_ + tt] - mx);
      su += e; ga = fmaf(nu_s[tt], e, ga);
    }
    gain_s[t] = ga / su;
  }
  const int i0 = (int)preds[(size_t)b * S_];
  __syncthreads();
  if (w == 0) {
    const float lam = log1pf(expf(clam[0]));
    float s = (l < K_) ? sc_s[l] + lam * gain_s[l] : -1e30f;
    if (l < K_ && l == i0) s = -100.f;
    if (l < K_) logits[(size_t)b * (S_ * K_) + K_ + l] = s;
    int bi = (l < K_) ? l : K_;
    float sm = s;
#pragma unroll
    for (int o2 = 32; o2; o2 >>= 1) {
      const float s2 = __shfl_xor(sm, o2);
      const int i2 = __shfl_xor(bi, o2);
      if (s2 > sm || (s2 == sm && i2 < bi)) { sm = s2; bi = i2; }
    }
    if (l == 0) preds[(size_t)b * S_ + 1] = (float)bi;
  }
}

extern "C" void kernel_launch(void* const* d_in, const int* in_sizes, int n_in,
                              void* d_out, int out_size, void* d_ws, size_t ws_size,
                              hipStream_t stream)
{
  const float* query_emb = (const float*)d_in[0];
  const float* cand_emb  = (const float*)d_in[1];
  const float* W_in = (const float*)d_in[2];
  const float* Wq_a = (const float*)d_in[3];
  const float* Wk_a = (const float*)d_in[4];
  const float* Wv_a = (const float*)d_in[5];
  const float* bq_a = (const float*)d_in[6];
  const float* bk_a = (const float*)d_in[7];
  const float* bv_a = (const float*)d_in[8];
  const float* Wo_a = (const float*)d_in[9];
  const float* bo_a = (const float*)d_in[10];
  const float* ln_w = (const float*)d_in[11];
  const float* ln_b = (const float*)d_in[12];
  const float* Wq   = (const float*)d_in[13];
  const float* Wc   = (const float*)d_in[14];
  const float* W_ih = (const float*)d_in[15];
  const float* W_hh = (const float*)d_in[16];
  const float* b_ih = (const float*)d_in[17];
  const float* b_hh = (const float*)d_in[18];
  const float* step_emb = (const float*)d_in[19];
  const float* tpro = (const float*)d_in[20];
  const float* Wqt  = (const float*)d_in[21];
  const float* bqt  = (const float*)d_in[22];
  const float* clam = (const float*)d_in[23];

  float* ws = (float*)d_ws;
  size_t o = 0;
  float* WkinT = ws + o; o += (size_t)D_ * H_;
  float* Wv_in = ws + o; o += (size_t)H_ * D_;
  ushort* BhW  = (ushort*)(ws + o); o += 98304;
  ushort* BlW  = (ushort*)(ws + o); o += 98304;
  float* pro   = ws + o; o += (size_t)T_ * H_;
  float* Bqk   = ws + o; o += (size_t)D_ * H_;
  float* bqk   = ws + o; o += 1024;
  float* Wvo   = ws + o; o += (size_t)H_ * D_;
  float* bvo   = ws + o; o += 256;
  float* Wqp   = ws + o; o += (size_t)H_ * H_;
  float* bqp   = ws + o; o += 256;
  float* vqbk  = ws + o; o += 256;
  float* qcst  = ws + o; o += 4;
  ushort* WintH = (ushort*)(ws + o); o += 98304;
  ushort* WintL = (ushort*)(ws + o); o += 98304;
  ushort* BqktH = (ushort*)(ws + o); o += 98304;
  ushort* BqktL = (ushort*)(ws + o); o += 98304;
  ushort* WvotH = (ushort*)(ws + o); o += 98304;
  ushort* WvotL = (ushort*)(ws + o); o += 98304;
  ushort* WqptH = (ushort*)(ws + o); o += 32768;
  ushort* WqptL = (ushort*)(ws + o); o += 32768;
  ushort* WihtH = (ushort*)(ws + o); o += 98304;
  ushort* WihtL = (ushort*)(ws + o); o += 98304;
  ushort* WhhtH = (ushort*)(ws + o); o += 98304;
  ushort* WhhtL = (ushort*)(ws + o); o += 98304;
  float* qr    = ws + o; o += (size_t)B_ * H_;
  float* qkv   = ws + o; o += (size_t)B_ * D_;   // later: gi
  float* wce   = ws + o; o += (size_t)B_ * D_;   // later: gh
  float* ctxb  = ws + o; o += (size_t)B_ * H_;   // hraw
  float* xhat  = ws + o; o += (size_t)B_ * H_;
  float* h     = ws + o; o += (size_t)B_ * H_;
  float* need  = ws + o; o += (size_t)B_ * T_;
  float* cn    = ws + o; o += (size_t)B_ * K_ * H_;
  float* cov   = ws + o; o += (size_t)B_ * T_;
  float* chosen= ws + o; o += (size_t)B_ * H_;

  float* out_logits = (float*)d_out;
  float* out_preds  = (float*)d_out + (size_t)B_ * S_ * K_;

  // weight folding + tiling
  fold_kernel<<<dim3(H_, 3), 256, 0, stream>>>(Wk_a, Wv_a, Wc, W_in, WkinT, Wv_in, BhW, BlW);
  proto_kernel<<<1, 256, 0, stream>>>(tpro, pro);
  fold2_kernel<<<D_, 256, 0, stream>>>(Wq_a, bq_a, bk_a, Wo_a, bo_a, bv_a, Wq, ln_w, ln_b,
                                       WkinT, Wv_in, Bqk, bqk, Wvo, bvo, Wqp, bqp, vqbk, qcst);
  TileJobs jobs;
  jobs.j[0] = {W_in, WintH, WintL, 16, 768, 256};
  jobs.j[1] = {Bqk,  BqktH, BqktL, 48, 256, 768};
  jobs.j[2] = {Wvo,  WvotH, WvotL, 16, 768, 256};
  jobs.j[3] = {Wqp,  WqptH, WqptL, 16, 256, 256};
  jobs.j[4] = {W_ih, WihtH, WihtL, 48, 256, 768};
  jobs.j[5] = {W_hh, WhhtH, WhhtL, 48, 256, 768};
  tile_all<<<dim3(768, 6), 256, 0, stream>>>(jobs);

  // query path
  gemm_bf<24, 16, false><<<dim3(B_ / 128, 4), 256, 0, stream>>>(query_emb, WintH, WintL, nullptr, qr);
  gemm_bf<8, 48, true><<<dim3(B_ / 128, 12), 256, 0, stream>>>(qr, BqktH, BqktL, bqk, qkv);

  // candidate path + fused attention
  gemm_cn_attn<<<(B_ * K_) / 64, 256, 0, stream>>>(cand_emb, BhW, BlW, qkv, qr, vqbk, qcst, cn, wce);

  // ctx gemm + residual + LN fused
  gemm_ctx_ln<<<B_ / 64, 256, 0, stream>>>(wce, WvotH, WvotL, bvo, qr, xhat);
  gemm_bf<8, 16, true><<<dim3(B_ / 128, 4), 256, 0, stream>>>(xhat, WqptH, WqptL, bqp, ctxb);  // hraw
  h_post<<<B_ / 4, 256, 0, stream>>>(ctxb, Wqt, bqt, h, need);

  // step 0 (scores + covered + chosen)
  score0_kernel<<<B_, 256, 0, stream>>>(h, step_emb, cn, pro, cov, chosen, out_logits, out_preds);
  // GRU gates
  gemm_bf<8, 48, true><<<dim3(B_ / 128, 12), 256, 0, stream>>>(chosen, WihtH, WihtL, b_ih, qkv);  // gi
  gemm_bf<8, 48, true><<<dim3(B_ / 128, 12), 256, 0, stream>>>(h, WhhtH, WhhtL, b_hh, wce);       // gh
  // step 1 (GRU + scores + topic gain)
  score1_kernel<<<B_, 256, 0, stream>>>(qkv, wce, h, step_emb, cn, pro, need, clam, cov,
                                        out_logits, out_preds);
}